// Round 7
// baseline (251.263 us; speedup 1.0000x reference)
//
#include <hip/hip_runtime.h>
#include <hip/hip_bf16.h>

#define NPIX 3136
#define BB 4
#define NSPLIT 5
#define LOG2E 1.4426950408889634f
#define ZLS 264  // LDS z-tile stride in u16 (wz+ff1 fusion)

typedef unsigned short u16;
typedef __bf16 bf16x8 __attribute__((ext_vector_type(8)));
typedef float f32x4 __attribute__((ext_vector_type(4)));

__device__ __forceinline__ float b2f(u16 u) {
  union { unsigned u; float f; } c; c.u = ((unsigned)u) << 16; return c.f;
}
__device__ __forceinline__ u16 f2b(float f) {
  __hip_bfloat16 h = __float2bfloat16(f);
  return *reinterpret_cast<u16*>(&h);
}
__device__ __forceinline__ unsigned pk2(float a, float b) {
  return (unsigned)f2b(a) | ((unsigned)f2b(b) << 16);
}
__device__ __forceinline__ f32x4 mfma(bf16x8 a, bf16x8 b, f32x4 c) {
  return __builtin_amdgcn_mfma_f32_16x16x32_bf16(a, b, c, 0, 0, 0);
}
// Raw v_exp_f32: scores are |x| << 126 so the compiler's denormal-guard
// expansion (~5 VALU ops) around llvm.exp2 is dead weight.
__device__ __forceinline__ float fast_exp2(float x) {
#if __has_builtin(__builtin_amdgcn_exp2f)
  return __builtin_amdgcn_exp2f(x);
#else
  float r; asm("v_exp_f32 %0, %1" : "=v"(r) : "v"(x)); return r;
#endif
}

// ---------------------------------------------------------------------------
// 2-tile MFMA wave-GEMM (R10/R2 shape -- best measured for proj).
// ---------------------------------------------------------------------------
template<int NSTEP, int NOT>
__device__ __forceinline__ void mf_gemm2(const u16* __restrict__ A0,
                                         const u16* __restrict__ A1,
                                         const u16* __restrict__ Brow, int sB,
                                         int lq, f32x4* acc) {
#pragma unroll
  for (int s = 0; s < NSTEP; ++s) {
    bf16x8 bf[NOT];
#pragma unroll
    for (int ot = 0; ot < NOT; ++ot)
      bf[ot] = *(const bf16x8*)(Brow + (size_t)ot * 16 * sB + s * 32 + lq * 8);
    bf16x8 a0 = *(const bf16x8*)(A0 + s * 32 + lq * 8);
    bf16x8 a1 = *(const bf16x8*)(A1 + s * 32 + lq * 8);
#pragma unroll
    for (int ot = 0; ot < NOT; ++ot) {
      acc[ot] = mfma(a0, bf[ot], acc[ot]);
      acc[NOT + ot] = mfma(a1, bf[ot], acc[NOT + ot]);
    }
  }
}

// ---------------------------------------------------------------------------
// prep_w: weights -> bf16. theta weights pre-scaled by log2(e).
// ---------------------------------------------------------------------------
__global__ __launch_bounds__(256) void prep_w(
    const float* __restrict__ gw, const float* __restrict__ tw,
    const float* __restrict__ pw, const float* __restrict__ Ww,
    const float* __restrict__ f1w, const float* __restrict__ f2w,
    const float* __restrict__ f3w,
    u16* __restrict__ gwb, u16* __restrict__ twb, u16* __restrict__ pwb,
    u16* __restrict__ Wwb, u16* __restrict__ f1b, u16* __restrict__ f3b,
    u16* __restrict__ f2p) {
  for (int i = blockIdx.x * 256 + threadIdx.x; i < 200704; i += gridDim.x * 256) {
    int j = i;
    if (j < 32768) { gwb[j] = f2b(gw[j]); continue; } j -= 32768;
    if (j < 32768) { twb[j] = f2b(tw[j] * LOG2E); continue; } j -= 32768;
    if (j < 32768) { pwb[j] = f2b(pw[j]); continue; } j -= 32768;
    if (j < 32768) { Wwb[j] = f2b(Ww[j]); continue; } j -= 32768;
    if (j < 16384) { f1b[j] = f2b(f1w[j]); continue; } j -= 16384;
    if (j < 16384) { f3b[j] = f2b(f3w[j]); continue; } j -= 16384;
    int t = j >> 12, rem = j & 4095, co = rem >> 6, ci = rem & 63;
    f2p[j] = f2b(f2w[(co * 64 + ci) * 9 + t]);
  }
}

// ---------------------------------------------------------------------------
// prep_x: xt[b][n][c] = bf16(x[b][c][n]) via 64x64 LDS tile transpose.
// ---------------------------------------------------------------------------
__global__ __launch_bounds__(256) void prep_x(const float* __restrict__ x,
                                              u16* __restrict__ xt) {
  __shared__ u16 sT[64 * 65];
  const int b = blockIdx.z, c0 = blockIdx.y * 64, n0 = blockIdx.x * 64;
  const int t = threadIdx.x;
#pragma unroll
  for (int cc = 0; cc < 4; ++cc) {
    int c = cc * 16 + (t >> 4), n4 = (t & 15) * 4;
    float4 v = *(const float4*)(x + ((size_t)(b * 256 + c0 + c)) * NPIX + n0 + n4);
    sT[c * 65 + n4 + 0] = f2b(v.x);
    sT[c * 65 + n4 + 1] = f2b(v.y);
    sT[c * 65 + n4 + 2] = f2b(v.z);
    sT[c * 65 + n4 + 3] = f2b(v.w);
  }
  __syncthreads();
#pragma unroll
  for (int nn = 0; nn < 4; ++nn) {
    int n = nn * 16 + (t >> 4), c4 = (t & 15) * 4;
    uint2 s;
    s.x = (unsigned)sT[(c4 + 0) * 65 + n] | ((unsigned)sT[(c4 + 1) * 65 + n] << 16);
    s.y = (unsigned)sT[(c4 + 2) * 65 + n] | ((unsigned)sT[(c4 + 3) * 65 + n] << 16);
    *(uint2*)(xt + ((size_t)b * NPIX + n0 + n) * 256 + c0 + c4) = s;
  }
}

// ---------------------------------------------------------------------------
// proj: R2 2-tile (best measured). Grid (25,6,BB).
// ---------------------------------------------------------------------------
__global__ __launch_bounds__(256) void proj_kernel(
    const u16* __restrict__ xt,
    const u16* __restrict__ gwb, const u16* __restrict__ twb, const u16* __restrict__ pwb,
    const float* __restrict__ gb, const float* __restrict__ tb, const float* __restrict__ pb,
    u16* __restrict__ gx, u16* __restrict__ Tq, u16* __restrict__ Pk) {
  const int b = blockIdx.z, oc = blockIdx.y, nb = blockIdx.x * 128;
  const int sec = oc >> 1, rbase = (oc & 1) * 64;
  const u16* wsel = sec == 0 ? gwb : (sec == 1 ? twb : pwb);
  const float* bsel = sec == 0 ? gb : (sec == 1 ? tb : pb);
  const int wv = threadIdx.x >> 6, lane = threadIdx.x & 63;
  const int lr = lane & 15, lq = lane >> 4;
  const int nrow0 = nb + wv * 32, nrow1 = nrow0 + 16;
  const int r0 = nrow0 + lr < NPIX ? nrow0 + lr : NPIX - 1;
  const int r1 = nrow1 + lr < NPIX ? nrow1 + lr : NPIX - 1;
  f32x4 acc[8] = {};
  mf_gemm2<8, 4>(xt + ((size_t)b * NPIX + r0) * 256,
                 xt + ((size_t)b * NPIX + r1) * 256,
                 wsel + (size_t)(rbase + lr) * 256, 256, lq, acc);
#pragma unroll
  for (int t = 0; t < 2; ++t) {
    const int qn = (t ? nrow1 : nrow0) + lq * 4;
    if (qn >= NPIX) continue;
#pragma unroll
    for (int ot = 0; ot < 4; ++ot) {
      const f32x4 a = acc[t * 4 + ot];
      const int o = rbase + ot * 16 + lr;
      float bias = bsel[o];
      if (sec == 1) bias *= LOG2E;
      if (sec == 0) {
        uint2 s;
        s.x = pk2(a[0] + bias, a[1] + bias);
        s.y = pk2(a[2] + bias, a[3] + bias);
        *(uint2*)(gx + ((size_t)b * 128 + o) * NPIX + qn) = s;
      } else {
        const int g = o >> 5, dl = o & 31;
        u16* dst = sec == 1 ? Tq : Pk;
        size_t base = (size_t)(b * 4 + g) * NPIX;
#pragma unroll
        for (int r = 0; r < 4; ++r)
          dst[(base + qn + r) * 32 + dl] = f2b(a[r] + bias);
      }
    }
  }
}

// ---------------------------------------------------------------------------
// attn: R12 form (best measured: 66.0us, plateau confirmed over R13/R14).
// ---------------------------------------------------------------------------
__global__ __launch_bounds__(256) void attn_kernel(
    const u16* __restrict__ Tq, const u16* __restrict__ Pk,
    const u16* __restrict__ gx, u16* __restrict__ OPb, float* __restrict__ LP) {
  __shared__ __align__(16) u16 Plds[4][32][40];
  const int bid = blockIdx.x;
  const int ks = bid / 400, rem = bid % 400;
  const int bg = rem / 25, qblk = rem % 25;
  const int b = bg >> 2, g = bg & 3;
  const int wave = threadIdx.x >> 6, lane = threadIdx.x & 63;
  const int lr = lane & 15, lq = lane >> 4;
  const int qbase = qblk * 128 + wave * 32;
  const int kc0 = ((ks * 98) / NSPLIT) * 32;
  const int kc1 = (((ks + 1) * 98) / NSPLIT) * 32;
  const u16* Qp = Tq + (size_t)bg * NPIX * 32;
  const u16* Kp = Pk + (size_t)bg * NPIX * 32;
  const u16* Vp = gx + ((size_t)b * 128 + g * 32) * NPIX;

  bf16x8 qf[2];
#pragma unroll
  for (int qi = 0; qi < 2; ++qi) {
    int row = qbase + qi * 16 + lr;
    row = row < NPIX ? row : NPIX - 1;
    qf[qi] = *(const bf16x8*)(Qp + (size_t)row * 32 + lq * 8);
  }
  const f32x4 z4 = {0.f, 0.f, 0.f, 0.f};
  f32x4 O[2][2], Lf[2];
#pragma unroll
  for (int qi = 0; qi < 2; ++qi) { O[qi][0] = z4; O[qi][1] = z4; Lf[qi] = z4; }
  bf16x8 onef;
#pragma unroll
  for (int j = 0; j < 8; ++j) onef[j] = (__bf16)1.0f;

#pragma unroll 1
  for (int kc = kc0; kc < kc1; kc += 32) {
    bf16x8 kf0 = *(const bf16x8*)(Kp + (size_t)(kc + lr) * 32 + lq * 8);
    bf16x8 kf1 = *(const bf16x8*)(Kp + (size_t)(kc + 16 + lr) * 32 + lq * 8);
    // Swapped operands: St[kt][qi] lane(lq,lr) reg r =
    //   score(k = kc + kt*16 + lq*4 + r, q = qbase + qi*16 + lr)
    f32x4 St[2][2];
    St[0][0] = mfma(kf0, qf[0], z4);
    St[0][1] = mfma(kf0, qf[1], z4);
    St[1][0] = mfma(kf1, qf[0], z4);
    St[1][1] = mfma(kf1, qf[1], z4);
#pragma unroll
    for (int kt = 0; kt < 2; ++kt)
#pragma unroll
      for (int qi = 0; qi < 2; ++qi) {
        const f32x4 s = St[kt][qi];
        unsigned e0 = __builtin_bit_cast(unsigned, fast_exp2(s[0]));
        unsigned e1 = __builtin_bit_cast(unsigned, fast_exp2(s[1]));
        unsigned e2 = __builtin_bit_cast(unsigned, fast_exp2(s[2]));
        unsigned e3 = __builtin_bit_cast(unsigned, fast_exp2(s[3]));
        uint2 pk;  // [bf16(e0),bf16(e1)] , [bf16(e2),bf16(e3)] (high-16 trunc)
        pk.x = __builtin_amdgcn_perm(e1, e0, 0x07060302u);
        pk.y = __builtin_amdgcn_perm(e3, e2, 0x07060302u);
        *(uint2*)(&Plds[wave][qi * 16 + lr][kt * 16 + lq * 4]) = pk;
      }
    bf16x8 pf0 = *(const bf16x8*)(&Plds[wave][lr][lq * 8]);
    bf16x8 pf1 = *(const bf16x8*)(&Plds[wave][16 + lr][lq * 8]);
    bf16x8 vf0 = *(const bf16x8*)(Vp + (size_t)lr * NPIX + kc + lq * 8);
    bf16x8 vf1 = *(const bf16x8*)(Vp + (size_t)(16 + lr) * NPIX + kc + lq * 8);
    O[0][0] = mfma(pf0, vf0, O[0][0]);
    O[0][1] = mfma(pf0, vf1, O[0][1]);
    O[1][0] = mfma(pf1, vf0, O[1][0]);
    O[1][1] = mfma(pf1, vf1, O[1][1]);
    Lf[0] = mfma(pf0, onef, Lf[0]);
    Lf[1] = mfma(pf1, onef, Lf[1]);
  }
  const size_t sbase = (size_t)(ks * 16 + bg) * NPIX;
#pragma unroll
  for (int qi = 0; qi < 2; ++qi) {
#pragma unroll
    for (int r = 0; r < 4; ++r) {
      int qrow = qbase + qi * 16 + lq * 4 + r;
      if (qrow < NPIX) {
        size_t ob = (sbase + qrow) * 32;
        OPb[ob + lr] = f2b(O[qi][0][r]);
        OPb[ob + 16 + lr] = f2b(O[qi][1][r]);
        if (lr == 0) LP[sbase + qrow] = Lf[qi][r];
      }
    }
  }
}

// ---------------------------------------------------------------------------
// wz+ff1 fused (R16, verified -13us): phase 1 = R2 wz -> zt + LDS z-tile;
// phase 2 = ff1 (8 MFMAs/wave from LDS) -> o1t.
// ---------------------------------------------------------------------------
__global__ __launch_bounds__(512) void wz_kernel(
    const u16* __restrict__ OPb, const float* __restrict__ LP,
    const u16* __restrict__ Wwb, const float* __restrict__ Wb,
    const float* __restrict__ sc, const float* __restrict__ bi,
    const float* __restrict__ mu, const float* __restrict__ var,
    const float* __restrict__ x,
    const u16* __restrict__ f1b, const float* __restrict__ s1,
    const float* __restrict__ b1, const float* __restrict__ m1,
    const float* __restrict__ v1,
    u16* __restrict__ zt, u16* __restrict__ o1t) {
  __shared__ float Ls[4][32];
  __shared__ __align__(16) u16 zl[32 * ZLS];
  const int b = blockIdx.y, nb = blockIdx.x * 32;
  const int tid = threadIdx.x;
  if (tid < 128) {
    int g = tid >> 5, row = tid & 31;
    float l = 0.f;
#pragma unroll
    for (int ks = 0; ks < NSPLIT; ++ks)
      l += LP[(size_t)(ks * 16 + b * 4 + g) * NPIX + nb + row];
    Ls[g][row] = 1.0f / l;
  }
  __syncthreads();
  const int wave = tid >> 6, lane = tid & 63;
  const int lr = lane & 15, lq = lane >> 4;
  const int oc = wave & 3, tt = wave >> 2;
  const int nrow = nb + tt * 16;
  f32x4 acc[4][4] = {};                // [g][ot]
#pragma unroll
  for (int g = 0; g < 4; ++g) {
    bf16x8 bf[4];
#pragma unroll
    for (int ot = 0; ot < 4; ++ot)
      bf[ot] = *(const bf16x8*)(Wwb + (size_t)(oc * 64 + ot * 16 + lr) * 128 + g * 32 + lq * 8);
#pragma unroll
    for (int ks = 0; ks < NSPLIT; ++ks) {
      bf16x8 af = *(const bf16x8*)(OPb +
          ((size_t)(ks * 16 + b * 4 + g) * NPIX + nrow + lr) * 32 + lq * 8);
#pragma unroll
      for (int ot = 0; ot < 4; ++ot)
        acc[g][ot] = mfma(af, bf[ot], acc[g][ot]);
    }
  }
#pragma unroll
  for (int ot = 0; ot < 4; ++ot) {
    const int o = oc * 64 + ot * 16 + lr;
    float inv = sc[o] * rsqrtf(var[o] + 1e-5f);
    float off = bi[o] - mu[o] * inv + Wb[o] * inv;
    const int qn = nrow + lq * 4;
    float4 xr = *(const float4*)(x + ((size_t)b * 256 + o) * NPIX + qn);
    float xv[4] = {xr.x, xr.y, xr.z, xr.w};
#pragma unroll
    for (int r = 0; r < 4; ++r) {
      int row = tt * 16 + lq * 4 + r;
      float y = acc[0][ot][r] * Ls[0][row] + acc[1][ot][r] * Ls[1][row] +
                acc[2][ot][r] * Ls[2][row] + acc[3][ot][r] * Ls[3][row];
      float v = fmaxf(y * inv + off + xv[r], 0.f);
      u16 vb = f2b(v);
      zt[((size_t)b * NPIX + qn + r) * 256 + o] = vb;
      zl[row * ZLS + o] = vb;
    }
  }
  __syncthreads();
  // ---- phase 2: ff1. Wave (tt2,oc2): 16 rows x 16 out-ch, K=256 from LDS.
  const int oc2 = wave & 3, tt2 = wave >> 2;
  f32x4 a1 = {0.f, 0.f, 0.f, 0.f};
  const u16* Bw = f1b + (size_t)(oc2 * 16 + lr) * 256;
#pragma unroll
  for (int s = 0; s < 8; ++s) {
    bf16x8 a0 = *(const bf16x8*)(&zl[(tt2 * 16 + lr) * ZLS + s * 32 + lq * 8]);
    bf16x8 bw = *(const bf16x8*)(Bw + s * 32 + lq * 8);
    a1 = mfma(a0, bw, a1);
  }
  const int o1 = oc2 * 16 + lr;
  float inv1 = s1[o1] * rsqrtf(v1[o1] + 1e-5f);
  float off1 = b1[o1] - m1[o1] * inv1;
  const int pr = nb + tt2 * 16 + lq * 4;
#pragma unroll
  for (int r = 0; r < 4; ++r) {
    float v = fmaxf(a1[r] * inv1 + off1, 0.f);
    o1t[((size_t)b * NPIX + pr + r) * 64 + o1] = f2b(v);
  }
}

// ---------------------------------------------------------------------------
// ff2+ff3 fused (R17): 512 threads, grid (25,BB). Phase 1 = ff2 im2col
// (wave: 16 rows x 64 oc, 72 MFMAs -- same per-wave shape as R2 ff2),
// o2 staged in LDS [128][72-stride]. Phase 2 = ff3 (wave: 64 rows x 64 oc,
// 32 MFMAs, B-frags register-resident) + bn3 + z-residual + fp32 out.
// Deletes the ff3 launch and the o2t global round-trip.
// ---------------------------------------------------------------------------
__global__ __launch_bounds__(512) void ff23_kernel(
    const u16* __restrict__ o1t, const u16* __restrict__ f2p,
    const float* __restrict__ s2, const float* __restrict__ b2,
    const float* __restrict__ m2, const float* __restrict__ v2,
    const u16* __restrict__ f3b,
    const float* __restrict__ s3, const float* __restrict__ b3,
    const float* __restrict__ m3, const float* __restrict__ v3,
    const u16* __restrict__ zt, float* __restrict__ out) {
  __shared__ __align__(16) u16 o2l[128 * 72];
  const int b = blockIdx.y, nb = blockIdx.x * 128;
  const int tid = threadIdx.x;
  const int wave = tid >> 6, lane = tid & 63;
  const int lr = lane & 15, lq = lane >> 4;
  // ---- phase 1: ff2 (16 rows x 64 oc per wave)
  {
    const int n0 = nb + wave * 16 + lr;
    const int n0c = n0 < NPIX ? n0 : NPIX - 1;
    const int h0 = n0c / 56, w0 = n0c % 56;
    f32x4 acc2[4] = {};
#pragma unroll
    for (int t = 0; t < 9; ++t) {
      const int dh = t / 3 - 1, dw = t % 3 - 1;
      const bool v0 = n0 < NPIX && (h0 + dh) >= 0 && (h0 + dh) < 56 &&
                      (w0 + dw) >= 0 && (w0 + dw) < 56;
      const u16* A0 = o1t + ((size_t)b * NPIX + n0c + dh * 56 + dw) * 64;
      const u16* Br = f2p + (size_t)t * 4096 + (size_t)lr * 64;
#pragma unroll
      for (int k2 = 0; k2 < 2; ++k2) {
        bf16x8 a0 = {};
        if (v0) a0 = *(const bf16x8*)(A0 + k2 * 32 + lq * 8);
#pragma unroll
        for (int ot = 0; ot < 4; ++ot) {
          bf16x8 bf = *(const bf16x8*)(Br + (size_t)ot * 16 * 64 + k2 * 32 + lq * 8);
          acc2[ot] = mfma(a0, bf, acc2[ot]);
        }
      }
    }
#pragma unroll
    for (int ot = 0; ot < 4; ++ot) {
      const int o = ot * 16 + lr;
      float inv = s2[o] * rsqrtf(v2[o] + 1e-5f);
      float off = b2[o] - m2[o] * inv;
#pragma unroll
      for (int r = 0; r < 4; ++r) {
        float v = fmaxf(acc2[ot][r] * inv + off, 0.f);
        o2l[(wave * 16 + lq * 4 + r) * 72 + o] = f2b(v);
      }
    }
  }
  __syncthreads();
  // ---- phase 2: ff3 (64 rows x 64 oc per wave)
  const int oc3 = wave & 3, tt3 = wave >> 2;
  bf16x8 bf3[4][2];
#pragma unroll
  for (int ot = 0; ot < 4; ++ot)
#pragma unroll
    for (int s = 0; s < 2; ++s)
      bf3[ot][s] = *(const bf16x8*)(f3b +
          (size_t)(oc3 * 64 + ot * 16 + lr) * 64 + s * 32 + lq * 8);
#pragma unroll
  for (int rt = 0; rt < 4; ++rt) {
    const int lrow = tt3 * 64 + rt * 16;
    bf16x8 a0 = *(const bf16x8*)(&o2l[(lrow + lr) * 72 + lq * 8]);
    bf16x8 a1 = *(const bf16x8*)(&o2l[(lrow + lr) * 72 + 32 + lq * 8]);
    f32x4 acc3[4] = {};
#pragma unroll
    for (int ot = 0; ot < 4; ++ot) {
      acc3[ot] = mfma(a0, bf3[ot][0], acc3[ot]);
      acc3[ot] = mfma(a1, bf3[ot][1], acc3[ot]);
    }
    const int qn = nb + lrow + lq * 4;
    if (qn < NPIX) {
#pragma unroll
      for (int ot = 0; ot < 4; ++ot) {
        const int o = oc3 * 64 + ot * 16 + lr;
        float inv = s3[o] * rsqrtf(v3[o] + 1e-5f);
        float off = b3[o] - m3[o] * inv;
        float4 sv4;
        float* sv = (float*)&sv4;
#pragma unroll
        for (int r = 0; r < 4; ++r) {
          float zres = b2f(zt[((size_t)b * NPIX + qn + r) * 256 + o]);
          sv[r] = fmaxf(acc3[ot][r] * inv + off + zres, 0.f);
        }
        *(float4*)(out + ((size_t)b * 256 + o) * NPIX + qn) = sv4;
      }
    }
  }
}

// ---------------------------------------------------------------------------
extern "C" void kernel_launch(void* const* d_in, const int* in_sizes, int n_in,
                              void* d_out, int out_size, void* d_ws, size_t ws_size,
                              hipStream_t stream) {
  const float* x    = (const float*)d_in[0];
  const float* gw   = (const float*)d_in[1];
  const float* gb   = (const float*)d_in[2];
  const float* tw   = (const float*)d_in[3];
  const float* tb   = (const float*)d_in[4];
  const float* pw   = (const float*)d_in[5];
  const float* pb   = (const float*)d_in[6];
  const float* Ww   = (const float*)d_in[7];
  const float* Wb   = (const float*)d_in[8];
  const float* bnWs = (const float*)d_in[9];
  const float* bnWb = (const float*)d_in[10];
  const float* bnWm = (const float*)d_in[11];
  const float* bnWv = (const float*)d_in[12];
  const float* f1w  = (const float*)d_in[13];
  const float* b1s  = (const float*)d_in[14];
  const float* b1b  = (const float*)d_in[15];
  const float* b1m  = (const float*)d_in[16];
  const float* b1v  = (const float*)d_in[17];
  const float* f2w  = (const float*)d_in[18];
  const float* b2s  = (const float*)d_in[19];
  const float* b2b  = (const float*)d_in[20];
  const float* b2m  = (const float*)d_in[21];
  const float* b2v  = (const float*)d_in[22];
  const float* f3w  = (const float*)d_in[23];
  const float* b3s  = (const float*)d_in[24];
  const float* b3b  = (const float*)d_in[25];
  const float* b3m  = (const float*)d_in[26];
  const float* b3v  = (const float*)d_in[27];
  float* out = (float*)d_out;

  u16* p = (u16*)d_ws;
  u16* xt  = p; p += (size_t)BB * NPIX * 256;
  u16* gwb = p; p += 128 * 256;
  u16* twb = p; p += 128 * 256;
  u16* pwb = p; p += 128 * 256;
  u16* Wwb = p; p += 256 * 128;
  u16* f1b = p; p += 64 * 256;
  u16* f3b = p; p += 256 * 64;
  u16* f2p = p; p += 9 * 64 * 64;
  u16* Tq  = p; p += (size_t)16 * NPIX * 32;
  u16* Pk  = p; p += (size_t)16 * NPIX * 32;
  u16* gx  = p; p += (size_t)BB * 128 * NPIX;
  u16* OPb = p; p += (size_t)7 * 16 * NPIX * 32;   // bump kept at 7 (upper bound)
  float* LP = (float*)p; p += (size_t)7 * 16 * NPIX * 2;
  u16* zt  = p; p += (size_t)BB * NPIX * 256;
  u16* o1t = p; p += (size_t)BB * NPIX * 64;
  u16* o2t = p; p += (size_t)BB * NPIX * 64;       // unused since R17 (kept for layout)
  (void)o2t;

  prep_w<<<dim3(196), 256, 0, stream>>>(gw, tw, pw, Ww, f1w, f2w, f3w,
                                        gwb, twb, pwb, Wwb, f1b, f3b, f2p);
  prep_x<<<dim3(49, 4, BB), 256, 0, stream>>>(x, xt);
  proj_kernel<<<dim3(25, 6, BB), 256, 0, stream>>>(xt, gwb, twb, pwb, gb, tb, pb,
                                                   gx, Tq, Pk);
  attn_kernel<<<dim3(NSPLIT * 400), 256, 0, stream>>>(Tq, Pk, gx, OPb, LP);
  wz_kernel<<<dim3(98, BB), 512, 0, stream>>>(OPb, LP, Wwb, Wb,
                                              bnWs, bnWb, bnWm, bnWv, x,
                                              f1b, b1s, b1b, b1m, b1v,
                                              zt, o1t);
  ff23_kernel<<<dim3(25, BB), 512, 0, stream>>>(o1t, f2p, b2s, b2b, b2m, b2v,
                                                f3b, b3s, b3b, b3m, b3v,
                                                zt, out);
}

// Round 8
// 249.046 us; speedup vs baseline: 1.0089x; 1.0089x over previous
//
#include <hip/hip_runtime.h>
#include <hip/hip_bf16.h>

#define NPIX 3136
#define BB 4
#define NSPLIT 5
#define LOG2E 1.4426950408889634f
#define ZLS 264  // LDS z-tile stride in u16 (wz+ff1 fusion)
#define O2S 72   // LDS o2-tile stride in u16 (ff2+ff3 fusion)

typedef unsigned short u16;
typedef __bf16 bf16x8 __attribute__((ext_vector_type(8)));
typedef float f32x4 __attribute__((ext_vector_type(4)));

__device__ __forceinline__ float b2f(u16 u) {
  union { unsigned u; float f; } c; c.u = ((unsigned)u) << 16; return c.f;
}
__device__ __forceinline__ u16 f2b(float f) {
  __hip_bfloat16 h = __float2bfloat16(f);
  return *reinterpret_cast<u16*>(&h);
}
__device__ __forceinline__ unsigned pk2(float a, float b) {
  return (unsigned)f2b(a) | ((unsigned)f2b(b) << 16);
}
__device__ __forceinline__ f32x4 mfma(bf16x8 a, bf16x8 b, f32x4 c) {
  return __builtin_amdgcn_mfma_f32_16x16x32_bf16(a, b, c, 0, 0, 0);
}
// Raw v_exp_f32: scores are |x| << 126 so the compiler's denormal-guard
// expansion (~5 VALU ops) around llvm.exp2 is dead weight.
__device__ __forceinline__ float fast_exp2(float x) {
#if __has_builtin(__builtin_amdgcn_exp2f)
  return __builtin_amdgcn_exp2f(x);
#else
  float r; asm("v_exp_f32 %0, %1" : "=v"(r) : "v"(x)); return r;
#endif
}

// ---------------------------------------------------------------------------
// 2-tile MFMA wave-GEMM (R10/R2 shape -- best measured for proj).
// ---------------------------------------------------------------------------
template<int NSTEP, int NOT>
__device__ __forceinline__ void mf_gemm2(const u16* __restrict__ A0,
                                         const u16* __restrict__ A1,
                                         const u16* __restrict__ Brow, int sB,
                                         int lq, f32x4* acc) {
#pragma unroll
  for (int s = 0; s < NSTEP; ++s) {
    bf16x8 bf[NOT];
#pragma unroll
    for (int ot = 0; ot < NOT; ++ot)
      bf[ot] = *(const bf16x8*)(Brow + (size_t)ot * 16 * sB + s * 32 + lq * 8);
    bf16x8 a0 = *(const bf16x8*)(A0 + s * 32 + lq * 8);
    bf16x8 a1 = *(const bf16x8*)(A1 + s * 32 + lq * 8);
#pragma unroll
    for (int ot = 0; ot < NOT; ++ot) {
      acc[ot] = mfma(a0, bf[ot], acc[ot]);
      acc[NOT + ot] = mfma(a1, bf[ot], acc[NOT + ot]);
    }
  }
}

// ---------------------------------------------------------------------------
// prep_w: weights -> bf16. theta weights pre-scaled by log2(e).
// ---------------------------------------------------------------------------
__global__ __launch_bounds__(256) void prep_w(
    const float* __restrict__ gw, const float* __restrict__ tw,
    const float* __restrict__ pw, const float* __restrict__ Ww,
    const float* __restrict__ f1w, const float* __restrict__ f2w,
    const float* __restrict__ f3w,
    u16* __restrict__ gwb, u16* __restrict__ twb, u16* __restrict__ pwb,
    u16* __restrict__ Wwb, u16* __restrict__ f1b, u16* __restrict__ f3b,
    u16* __restrict__ f2p) {
  for (int i = blockIdx.x * 256 + threadIdx.x; i < 200704; i += gridDim.x * 256) {
    int j = i;
    if (j < 32768) { gwb[j] = f2b(gw[j]); continue; } j -= 32768;
    if (j < 32768) { twb[j] = f2b(tw[j] * LOG2E); continue; } j -= 32768;
    if (j < 32768) { pwb[j] = f2b(pw[j]); continue; } j -= 32768;
    if (j < 32768) { Wwb[j] = f2b(Ww[j]); continue; } j -= 32768;
    if (j < 16384) { f1b[j] = f2b(f1w[j]); continue; } j -= 16384;
    if (j < 16384) { f3b[j] = f2b(f3w[j]); continue; } j -= 16384;
    int t = j >> 12, rem = j & 4095, co = rem >> 6, ci = rem & 63;
    f2p[j] = f2b(f2w[(co * 64 + ci) * 9 + t]);
  }
}

// ---------------------------------------------------------------------------
// prep_x: xt[b][n][c] = bf16(x[b][c][n]) via 64x64 LDS tile transpose.
// ---------------------------------------------------------------------------
__global__ __launch_bounds__(256) void prep_x(const float* __restrict__ x,
                                              u16* __restrict__ xt) {
  __shared__ u16 sT[64 * 65];
  const int b = blockIdx.z, c0 = blockIdx.y * 64, n0 = blockIdx.x * 64;
  const int t = threadIdx.x;
#pragma unroll
  for (int cc = 0; cc < 4; ++cc) {
    int c = cc * 16 + (t >> 4), n4 = (t & 15) * 4;
    float4 v = *(const float4*)(x + ((size_t)(b * 256 + c0 + c)) * NPIX + n0 + n4);
    sT[c * 65 + n4 + 0] = f2b(v.x);
    sT[c * 65 + n4 + 1] = f2b(v.y);
    sT[c * 65 + n4 + 2] = f2b(v.z);
    sT[c * 65 + n4 + 3] = f2b(v.w);
  }
  __syncthreads();
#pragma unroll
  for (int nn = 0; nn < 4; ++nn) {
    int n = nn * 16 + (t >> 4), c4 = (t & 15) * 4;
    uint2 s;
    s.x = (unsigned)sT[(c4 + 0) * 65 + n] | ((unsigned)sT[(c4 + 1) * 65 + n] << 16);
    s.y = (unsigned)sT[(c4 + 2) * 65 + n] | ((unsigned)sT[(c4 + 3) * 65 + n] << 16);
    *(uint2*)(xt + ((size_t)b * NPIX + n0 + n) * 256 + c0 + c4) = s;
  }
}

// ---------------------------------------------------------------------------
// proj: R2 2-tile (best measured). Grid (25,6,BB).
// ---------------------------------------------------------------------------
__global__ __launch_bounds__(256) void proj_kernel(
    const u16* __restrict__ xt,
    const u16* __restrict__ gwb, const u16* __restrict__ twb, const u16* __restrict__ pwb,
    const float* __restrict__ gb, const float* __restrict__ tb, const float* __restrict__ pb,
    u16* __restrict__ gx, u16* __restrict__ Tq, u16* __restrict__ Pk) {
  const int b = blockIdx.z, oc = blockIdx.y, nb = blockIdx.x * 128;
  const int sec = oc >> 1, rbase = (oc & 1) * 64;
  const u16* wsel = sec == 0 ? gwb : (sec == 1 ? twb : pwb);
  const float* bsel = sec == 0 ? gb : (sec == 1 ? tb : pb);
  const int wv = threadIdx.x >> 6, lane = threadIdx.x & 63;
  const int lr = lane & 15, lq = lane >> 4;
  const int nrow0 = nb + wv * 32, nrow1 = nrow0 + 16;
  const int r0 = nrow0 + lr < NPIX ? nrow0 + lr : NPIX - 1;
  const int r1 = nrow1 + lr < NPIX ? nrow1 + lr : NPIX - 1;
  f32x4 acc[8] = {};
  mf_gemm2<8, 4>(xt + ((size_t)b * NPIX + r0) * 256,
                 xt + ((size_t)b * NPIX + r1) * 256,
                 wsel + (size_t)(rbase + lr) * 256, 256, lq, acc);
#pragma unroll
  for (int t = 0; t < 2; ++t) {
    const int qn = (t ? nrow1 : nrow0) + lq * 4;
    if (qn >= NPIX) continue;
#pragma unroll
    for (int ot = 0; ot < 4; ++ot) {
      const f32x4 a = acc[t * 4 + ot];
      const int o = rbase + ot * 16 + lr;
      float bias = bsel[o];
      if (sec == 1) bias *= LOG2E;
      if (sec == 0) {
        uint2 s;
        s.x = pk2(a[0] + bias, a[1] + bias);
        s.y = pk2(a[2] + bias, a[3] + bias);
        *(uint2*)(gx + ((size_t)b * 128 + o) * NPIX + qn) = s;
      } else {
        const int g = o >> 5, dl = o & 31;
        u16* dst = sec == 1 ? Tq : Pk;
        size_t base = (size_t)(b * 4 + g) * NPIX;
#pragma unroll
        for (int r = 0; r < 4; ++r)
          dst[(base + qn + r) * 32 + dl] = f2b(a[r] + bias);
      }
    }
  }
}

// ---------------------------------------------------------------------------
// attn: R12 form (best measured: 66.0us, plateau confirmed over R13/R14).
// ---------------------------------------------------------------------------
__global__ __launch_bounds__(256) void attn_kernel(
    const u16* __restrict__ Tq, const u16* __restrict__ Pk,
    const u16* __restrict__ gx, u16* __restrict__ OPb, float* __restrict__ LP) {
  __shared__ __align__(16) u16 Plds[4][32][40];
  const int bid = blockIdx.x;
  const int ks = bid / 400, rem = bid % 400;
  const int bg = rem / 25, qblk = rem % 25;
  const int b = bg >> 2, g = bg & 3;
  const int wave = threadIdx.x >> 6, lane = threadIdx.x & 63;
  const int lr = lane & 15, lq = lane >> 4;
  const int qbase = qblk * 128 + wave * 32;
  const int kc0 = ((ks * 98) / NSPLIT) * 32;
  const int kc1 = (((ks + 1) * 98) / NSPLIT) * 32;
  const u16* Qp = Tq + (size_t)bg * NPIX * 32;
  const u16* Kp = Pk + (size_t)bg * NPIX * 32;
  const u16* Vp = gx + ((size_t)b * 128 + g * 32) * NPIX;

  bf16x8 qf[2];
#pragma unroll
  for (int qi = 0; qi < 2; ++qi) {
    int row = qbase + qi * 16 + lr;
    row = row < NPIX ? row : NPIX - 1;
    qf[qi] = *(const bf16x8*)(Qp + (size_t)row * 32 + lq * 8);
  }
  const f32x4 z4 = {0.f, 0.f, 0.f, 0.f};
  f32x4 O[2][2], Lf[2];
#pragma unroll
  for (int qi = 0; qi < 2; ++qi) { O[qi][0] = z4; O[qi][1] = z4; Lf[qi] = z4; }
  bf16x8 onef;
#pragma unroll
  for (int j = 0; j < 8; ++j) onef[j] = (__bf16)1.0f;

#pragma unroll 1
  for (int kc = kc0; kc < kc1; kc += 32) {
    bf16x8 kf0 = *(const bf16x8*)(Kp + (size_t)(kc + lr) * 32 + lq * 8);
    bf16x8 kf1 = *(const bf16x8*)(Kp + (size_t)(kc + 16 + lr) * 32 + lq * 8);
    // Swapped operands: St[kt][qi] lane(lq,lr) reg r =
    //   score(k = kc + kt*16 + lq*4 + r, q = qbase + qi*16 + lr)
    f32x4 St[2][2];
    St[0][0] = mfma(kf0, qf[0], z4);
    St[0][1] = mfma(kf0, qf[1], z4);
    St[1][0] = mfma(kf1, qf[0], z4);
    St[1][1] = mfma(kf1, qf[1], z4);
#pragma unroll
    for (int kt = 0; kt < 2; ++kt)
#pragma unroll
      for (int qi = 0; qi < 2; ++qi) {
        const f32x4 s = St[kt][qi];
        unsigned e0 = __builtin_bit_cast(unsigned, fast_exp2(s[0]));
        unsigned e1 = __builtin_bit_cast(unsigned, fast_exp2(s[1]));
        unsigned e2 = __builtin_bit_cast(unsigned, fast_exp2(s[2]));
        unsigned e3 = __builtin_bit_cast(unsigned, fast_exp2(s[3]));
        uint2 pk;  // [bf16(e0),bf16(e1)] , [bf16(e2),bf16(e3)] (high-16 trunc)
        pk.x = __builtin_amdgcn_perm(e1, e0, 0x07060302u);
        pk.y = __builtin_amdgcn_perm(e3, e2, 0x07060302u);
        *(uint2*)(&Plds[wave][qi * 16 + lr][kt * 16 + lq * 4]) = pk;
      }
    bf16x8 pf0 = *(const bf16x8*)(&Plds[wave][lr][lq * 8]);
    bf16x8 pf1 = *(const bf16x8*)(&Plds[wave][16 + lr][lq * 8]);
    bf16x8 vf0 = *(const bf16x8*)(Vp + (size_t)lr * NPIX + kc + lq * 8);
    bf16x8 vf1 = *(const bf16x8*)(Vp + (size_t)(16 + lr) * NPIX + kc + lq * 8);
    O[0][0] = mfma(pf0, vf0, O[0][0]);
    O[0][1] = mfma(pf0, vf1, O[0][1]);
    O[1][0] = mfma(pf1, vf0, O[1][0]);
    O[1][1] = mfma(pf1, vf1, O[1][1]);
    Lf[0] = mfma(pf0, onef, Lf[0]);
    Lf[1] = mfma(pf1, onef, Lf[1]);
  }
  const size_t sbase = (size_t)(ks * 16 + bg) * NPIX;
#pragma unroll
  for (int qi = 0; qi < 2; ++qi) {
#pragma unroll
    for (int r = 0; r < 4; ++r) {
      int qrow = qbase + qi * 16 + lq * 4 + r;
      if (qrow < NPIX) {
        size_t ob = (sbase + qrow) * 32;
        OPb[ob + lr] = f2b(O[qi][0][r]);
        OPb[ob + 16 + lr] = f2b(O[qi][1][r]);
        if (lr == 0) LP[sbase + qrow] = Lf[qi][r];
      }
    }
  }
}

// ---------------------------------------------------------------------------
// wz+ff1 fused (R16, verified -13us): phase 1 = R2 wz -> zt + LDS z-tile;
// phase 2 = ff1 (8 MFMAs/wave from LDS) -> o1t.
// ---------------------------------------------------------------------------
__global__ __launch_bounds__(512) void wz_kernel(
    const u16* __restrict__ OPb, const float* __restrict__ LP,
    const u16* __restrict__ Wwb, const float* __restrict__ Wb,
    const float* __restrict__ sc, const float* __restrict__ bi,
    const float* __restrict__ mu, const float* __restrict__ var,
    const float* __restrict__ x,
    const u16* __restrict__ f1b, const float* __restrict__ s1,
    const float* __restrict__ b1, const float* __restrict__ m1,
    const float* __restrict__ v1,
    u16* __restrict__ zt, u16* __restrict__ o1t) {
  __shared__ float Ls[4][32];
  __shared__ __align__(16) u16 zl[32 * ZLS];
  const int b = blockIdx.y, nb = blockIdx.x * 32;
  const int tid = threadIdx.x;
  if (tid < 128) {
    int g = tid >> 5, row = tid & 31;
    float l = 0.f;
#pragma unroll
    for (int ks = 0; ks < NSPLIT; ++ks)
      l += LP[(size_t)(ks * 16 + b * 4 + g) * NPIX + nb + row];
    Ls[g][row] = 1.0f / l;
  }
  __syncthreads();
  const int wave = tid >> 6, lane = tid & 63;
  const int lr = lane & 15, lq = lane >> 4;
  const int oc = wave & 3, tt = wave >> 2;
  const int nrow = nb + tt * 16;
  f32x4 acc[4][4] = {};                // [g][ot]
#pragma unroll
  for (int g = 0; g < 4; ++g) {
    bf16x8 bf[4];
#pragma unroll
    for (int ot = 0; ot < 4; ++ot)
      bf[ot] = *(const bf16x8*)(Wwb + (size_t)(oc * 64 + ot * 16 + lr) * 128 + g * 32 + lq * 8);
#pragma unroll
    for (int ks = 0; ks < NSPLIT; ++ks) {
      bf16x8 af = *(const bf16x8*)(OPb +
          ((size_t)(ks * 16 + b * 4 + g) * NPIX + nrow + lr) * 32 + lq * 8);
#pragma unroll
      for (int ot = 0; ot < 4; ++ot)
        acc[g][ot] = mfma(af, bf[ot], acc[g][ot]);
    }
  }
#pragma unroll
  for (int ot = 0; ot < 4; ++ot) {
    const int o = oc * 64 + ot * 16 + lr;
    float inv = sc[o] * rsqrtf(var[o] + 1e-5f);
    float off = bi[o] - mu[o] * inv + Wb[o] * inv;
    const int qn = nrow + lq * 4;
    float4 xr = *(const float4*)(x + ((size_t)b * 256 + o) * NPIX + qn);
    float xv[4] = {xr.x, xr.y, xr.z, xr.w};
#pragma unroll
    for (int r = 0; r < 4; ++r) {
      int row = tt * 16 + lq * 4 + r;
      float y = acc[0][ot][r] * Ls[0][row] + acc[1][ot][r] * Ls[1][row] +
                acc[2][ot][r] * Ls[2][row] + acc[3][ot][r] * Ls[3][row];
      float v = fmaxf(y * inv + off + xv[r], 0.f);
      u16 vb = f2b(v);
      zt[((size_t)b * NPIX + qn + r) * 256 + o] = vb;
      zl[row * ZLS + o] = vb;
    }
  }
  __syncthreads();
  // ---- phase 2: ff1. Wave (tt2,oc2): 16 rows x 16 out-ch, K=256 from LDS.
  const int oc2 = wave & 3, tt2 = wave >> 2;
  f32x4 a1 = {0.f, 0.f, 0.f, 0.f};
  const u16* Bw = f1b + (size_t)(oc2 * 16 + lr) * 256;
#pragma unroll
  for (int s = 0; s < 8; ++s) {
    bf16x8 a0 = *(const bf16x8*)(&zl[(tt2 * 16 + lr) * ZLS + s * 32 + lq * 8]);
    bf16x8 bw = *(const bf16x8*)(Bw + s * 32 + lq * 8);
    a1 = mfma(a0, bw, a1);
  }
  const int o1 = oc2 * 16 + lr;
  float inv1 = s1[o1] * rsqrtf(v1[o1] + 1e-5f);
  float off1 = b1[o1] - m1[o1] * inv1;
  const int pr = nb + tt2 * 16 + lq * 4;
#pragma unroll
  for (int r = 0; r < 4; ++r) {
    float v = fmaxf(a1[r] * inv1 + off1, 0.f);
    o1t[((size_t)b * NPIX + pr + r) * 64 + o1] = f2b(v);
  }
}

// ---------------------------------------------------------------------------
// ff2+ff3 fused v2 (R18): grid (98,BB) = 392 blocks (>=256 CUs -- the R17
// failure was 100 blocks leaving 61% of CUs idle), 512 threads, 32 rows per
// block (3136 = 98*32: no row-bound checks). Phase 1 = ff2 im2col: 8 waves
// = 2 row-tiles x 4 oc-quarters, 16 rows x 16 oc, 18 MFMAs/wave; o2 staged
// in LDS [32][O2S]. Phase 2 = ff3: 8 waves = 2 row-tiles x 4 oc-groups,
// 16 rows x 64 oc, 8 MFMAs/wave from LDS + bn3 + z-residual + fp32 out.
// Deletes the ff3 launch and the o2t global round-trip.
// ---------------------------------------------------------------------------
__global__ __launch_bounds__(512) void ff23_kernel(
    const u16* __restrict__ o1t, const u16* __restrict__ f2p,
    const float* __restrict__ s2, const float* __restrict__ b2,
    const float* __restrict__ m2, const float* __restrict__ v2,
    const u16* __restrict__ f3b,
    const float* __restrict__ s3, const float* __restrict__ b3,
    const float* __restrict__ m3, const float* __restrict__ v3,
    const u16* __restrict__ zt, float* __restrict__ out) {
  __shared__ __align__(16) u16 o2l[32 * O2S];
  const int b = blockIdx.y, nb = blockIdx.x * 32;
  const int tid = threadIdx.x;
  const int wave = tid >> 6, lane = tid & 63;
  const int lr = lane & 15, lq = lane >> 4;
  // ---- phase 1: ff2 (16 rows x 16 oc per wave; wave = rt*4 + oq)
  {
    const int rt = wave >> 2, oq = wave & 3;
    const int n0 = nb + rt * 16 + lr;        // < NPIX always
    const int h0 = n0 / 56, w0 = n0 % 56;
    f32x4 acc2 = {0.f, 0.f, 0.f, 0.f};
#pragma unroll
    for (int t = 0; t < 9; ++t) {
      const int dh = t / 3 - 1, dw = t % 3 - 1;
      const bool v0 = (h0 + dh) >= 0 && (h0 + dh) < 56 &&
                      (w0 + dw) >= 0 && (w0 + dw) < 56;
      const u16* A0 = o1t + ((size_t)b * NPIX + n0 + dh * 56 + dw) * 64;
      const u16* Br = f2p + (size_t)t * 4096 + (size_t)(oq * 16 + lr) * 64;
#pragma unroll
      for (int k2 = 0; k2 < 2; ++k2) {
        bf16x8 a0 = {};
        if (v0) a0 = *(const bf16x8*)(A0 + k2 * 32 + lq * 8);
        bf16x8 bf = *(const bf16x8*)(Br + k2 * 32 + lq * 8);
        acc2 = mfma(a0, bf, acc2);
      }
    }
    const int o = oq * 16 + lr;
    float inv = s2[o] * rsqrtf(v2[o] + 1e-5f);
    float off = b2[o] - m2[o] * inv;
#pragma unroll
    for (int r = 0; r < 4; ++r) {
      float v = fmaxf(acc2[r] * inv + off, 0.f);
      o2l[(rt * 16 + lq * 4 + r) * O2S + o] = f2b(v);
    }
  }
  __syncthreads();
  // ---- phase 2: ff3 (16 rows x 64 oc per wave; wave = rt2*4 + ocq)
  const int rt2 = wave >> 2, ocq = wave & 3;
  bf16x8 a0 = *(const bf16x8*)(&o2l[(rt2 * 16 + lr) * O2S + lq * 8]);
  bf16x8 a1 = *(const bf16x8*)(&o2l[(rt2 * 16 + lr) * O2S + 32 + lq * 8]);
  const int qn = nb + rt2 * 16 + lq * 4;     // < NPIX always
#pragma unroll
  for (int ot = 0; ot < 4; ++ot) {
    const int o = ocq * 64 + ot * 16 + lr;
    bf16x8 b0 = *(const bf16x8*)(f3b + (size_t)o * 64 + lq * 8);
    bf16x8 b1f = *(const bf16x8*)(f3b + (size_t)o * 64 + 32 + lq * 8);
    f32x4 acc3 = {0.f, 0.f, 0.f, 0.f};
    acc3 = mfma(a0, b0, acc3);
    acc3 = mfma(a1, b1f, acc3);
    float inv = s3[o] * rsqrtf(v3[o] + 1e-5f);
    float off = b3[o] - m3[o] * inv;
    float4 sv4;
    float* sv = (float*)&sv4;
#pragma unroll
    for (int r = 0; r < 4; ++r) {
      float zres = b2f(zt[((size_t)b * NPIX + qn + r) * 256 + o]);
      sv[r] = fmaxf(acc3[r] * inv + off + zres, 0.f);
    }
    *(float4*)(out + ((size_t)b * 256 + o) * NPIX + qn) = sv4;
  }
}

// ---------------------------------------------------------------------------
extern "C" void kernel_launch(void* const* d_in, const int* in_sizes, int n_in,
                              void* d_out, int out_size, void* d_ws, size_t ws_size,
                              hipStream_t stream) {
  const float* x    = (const float*)d_in[0];
  const float* gw   = (const float*)d_in[1];
  const float* gb   = (const float*)d_in[2];
  const float* tw   = (const float*)d_in[3];
  const float* tb   = (const float*)d_in[4];
  const float* pw   = (const float*)d_in[5];
  const float* pb   = (const float*)d_in[6];
  const float* Ww   = (const float*)d_in[7];
  const float* Wb   = (const float*)d_in[8];
  const float* bnWs = (const float*)d_in[9];
  const float* bnWb = (const float*)d_in[10];
  const float* bnWm = (const float*)d_in[11];
  const float* bnWv = (const float*)d_in[12];
  const float* f1w  = (const float*)d_in[13];
  const float* b1s  = (const float*)d_in[14];
  const float* b1b  = (const float*)d_in[15];
  const float* b1m  = (const float*)d_in[16];
  const float* b1v  = (const float*)d_in[17];
  const float* f2w  = (const float*)d_in[18];
  const float* b2s  = (const float*)d_in[19];
  const float* b2b  = (const float*)d_in[20];
  const float* b2m  = (const float*)d_in[21];
  const float* b2v  = (const float*)d_in[22];
  const float* f3w  = (const float*)d_in[23];
  const float* b3s  = (const float*)d_in[24];
  const float* b3b  = (const float*)d_in[25];
  const float* b3m  = (const float*)d_in[26];
  const float* b3v  = (const float*)d_in[27];
  float* out = (float*)d_out;

  u16* p = (u16*)d_ws;
  u16* xt  = p; p += (size_t)BB * NPIX * 256;
  u16* gwb = p; p += 128 * 256;
  u16* twb = p; p += 128 * 256;
  u16* pwb = p; p += 128 * 256;
  u16* Wwb = p; p += 256 * 128;
  u16* f1b = p; p += 64 * 256;
  u16* f3b = p; p += 256 * 64;
  u16* f2p = p; p += 9 * 64 * 64;
  u16* Tq  = p; p += (size_t)16 * NPIX * 32;
  u16* Pk  = p; p += (size_t)16 * NPIX * 32;
  u16* gx  = p; p += (size_t)BB * 128 * NPIX;
  u16* OPb = p; p += (size_t)7 * 16 * NPIX * 32;   // bump kept at 7 (upper bound)
  float* LP = (float*)p; p += (size_t)7 * 16 * NPIX * 2;
  u16* zt  = p; p += (size_t)BB * NPIX * 256;
  u16* o1t = p; p += (size_t)BB * NPIX * 64;
  u16* o2t = p; p += (size_t)BB * NPIX * 64;       // unused since R17 (kept for layout)
  (void)o2t;

  prep_w<<<dim3(196), 256, 0, stream>>>(gw, tw, pw, Ww, f1w, f2w, f3w,
                                        gwb, twb, pwb, Wwb, f1b, f3b, f2p);
  prep_x<<<dim3(49, 4, BB), 256, 0, stream>>>(x, xt);
  proj_kernel<<<dim3(25, 6, BB), 256, 0, stream>>>(xt, gwb, twb, pwb, gb, tb, pb,
                                                   gx, Tq, Pk);
  attn_kernel<<<dim3(NSPLIT * 400), 256, 0, stream>>>(Tq, Pk, gx, OPb, LP);
  wz_kernel<<<dim3(98, BB), 512, 0, stream>>>(OPb, LP, Wwb, Wb,
                                              bnWs, bnWb, bnWm, bnWv, x,
                                              f1b, b1s, b1b, b1m, b1v,
                                              zt, o1t);
  ff23_kernel<<<dim3(98, BB), 512, 0, stream>>>(o1t, f2p, b2s, b2b, b2m, b2v,
                                                f3b, b3s, b3b, b3m, b3v,
                                                zt, out);
}

// Round 9
// 237.892 us; speedup vs baseline: 1.0562x; 1.0469x over previous
//
#include <hip/hip_runtime.h>
#include <hip/hip_bf16.h>

#define NPIX 3136
#define BB 4
#define NSPLIT 5
#define LOG2E 1.4426950408889634f
#define ZLS 264  // LDS z-tile stride in u16 (wz+ff1 fusion)

typedef unsigned short u16;
typedef __bf16 bf16x8 __attribute__((ext_vector_type(8)));
typedef float f32x4 __attribute__((ext_vector_type(4)));

__device__ __forceinline__ float b2f(u16 u) {
  union { unsigned u; float f; } c; c.u = ((unsigned)u) << 16; return c.f;
}
__device__ __forceinline__ u16 f2b(float f) {
  __hip_bfloat16 h = __float2bfloat16(f);
  return *reinterpret_cast<u16*>(&h);
}
__device__ __forceinline__ unsigned pk2(float a, float b) {
  return (unsigned)f2b(a) | ((unsigned)f2b(b) << 16);
}
__device__ __forceinline__ f32x4 mfma(bf16x8 a, bf16x8 b, f32x4 c) {
  return __builtin_amdgcn_mfma_f32_16x16x32_bf16(a, b, c, 0, 0, 0);
}
// Raw v_exp_f32: scores are |x| << 126 so the compiler's denormal-guard
// expansion (~5 VALU ops) around llvm.exp2 is dead weight.
__device__ __forceinline__ float fast_exp2(float x) {
#if __has_builtin(__builtin_amdgcn_exp2f)
  return __builtin_amdgcn_exp2f(x);
#else
  float r; asm("v_exp_f32 %0, %1" : "=v"(r) : "v"(x)); return r;
#endif
}

// ---------------------------------------------------------------------------
// 2-tile MFMA wave-GEMM (R10/R2 shape -- best measured for proj/ff1/ff3).
// ---------------------------------------------------------------------------
template<int NSTEP, int NOT>
__device__ __forceinline__ void mf_gemm2(const u16* __restrict__ A0,
                                         const u16* __restrict__ A1,
                                         const u16* __restrict__ Brow, int sB,
                                         int lq, f32x4* acc) {
#pragma unroll
  for (int s = 0; s < NSTEP; ++s) {
    bf16x8 bf[NOT];
#pragma unroll
    for (int ot = 0; ot < NOT; ++ot)
      bf[ot] = *(const bf16x8*)(Brow + (size_t)ot * 16 * sB + s * 32 + lq * 8);
    bf16x8 a0 = *(const bf16x8*)(A0 + s * 32 + lq * 8);
    bf16x8 a1 = *(const bf16x8*)(A1 + s * 32 + lq * 8);
#pragma unroll
    for (int ot = 0; ot < NOT; ++ot) {
      acc[ot] = mfma(a0, bf[ot], acc[ot]);
      acc[NOT + ot] = mfma(a1, bf[ot], acc[NOT + ot]);
    }
  }
}

// ---------------------------------------------------------------------------
// prep_all (R19): prep_x (blocks 0..783) + prep_w (blocks 784..979) merged
// into ONE launch. The two jobs are independent; running them as one grid
// removes a dispatch boundary and fills the machine during prep.
// ---------------------------------------------------------------------------
__global__ __launch_bounds__(256) void prep_all(
    const float* __restrict__ x,
    const float* __restrict__ gw, const float* __restrict__ tw,
    const float* __restrict__ pw, const float* __restrict__ Ww,
    const float* __restrict__ f1w, const float* __restrict__ f2w,
    const float* __restrict__ f3w,
    u16* __restrict__ xt,
    u16* __restrict__ gwb, u16* __restrict__ twb, u16* __restrict__ pwb,
    u16* __restrict__ Wwb, u16* __restrict__ f1b, u16* __restrict__ f3b,
    u16* __restrict__ f2p) {
  __shared__ u16 sT[64 * 65];
  const int bid = blockIdx.x;
  const int t = threadIdx.x;
  if (bid < 784) {
    // ---- prep_x: 64x64 LDS tile transpose. bid -> (b, c0, n0).
    const int b = bid / 196, rem = bid % 196;
    const int c0 = (rem / 49) * 64, n0 = (rem % 49) * 64;
#pragma unroll
    for (int cc = 0; cc < 4; ++cc) {
      int c = cc * 16 + (t >> 4), n4 = (t & 15) * 4;
      float4 v = *(const float4*)(x + ((size_t)(b * 256 + c0 + c)) * NPIX + n0 + n4);
      sT[c * 65 + n4 + 0] = f2b(v.x);
      sT[c * 65 + n4 + 1] = f2b(v.y);
      sT[c * 65 + n4 + 2] = f2b(v.z);
      sT[c * 65 + n4 + 3] = f2b(v.w);
    }
    __syncthreads();
#pragma unroll
    for (int nn = 0; nn < 4; ++nn) {
      int n = nn * 16 + (t >> 4), c4 = (t & 15) * 4;
      uint2 s;
      s.x = (unsigned)sT[(c4 + 0) * 65 + n] | ((unsigned)sT[(c4 + 1) * 65 + n] << 16);
      s.y = (unsigned)sT[(c4 + 2) * 65 + n] | ((unsigned)sT[(c4 + 3) * 65 + n] << 16);
      *(uint2*)(xt + ((size_t)b * NPIX + n0 + n) * 256 + c0 + c4) = s;
    }
  } else {
    // ---- prep_w: weights -> bf16 (theta pre-scaled by log2e).
    for (int i = (bid - 784) * 256 + t; i < 200704; i += 196 * 256) {
      int j = i;
      if (j < 32768) { gwb[j] = f2b(gw[j]); continue; } j -= 32768;
      if (j < 32768) { twb[j] = f2b(tw[j] * LOG2E); continue; } j -= 32768;
      if (j < 32768) { pwb[j] = f2b(pw[j]); continue; } j -= 32768;
      if (j < 32768) { Wwb[j] = f2b(Ww[j]); continue; } j -= 32768;
      if (j < 16384) { f1b[j] = f2b(f1w[j]); continue; } j -= 16384;
      if (j < 16384) { f3b[j] = f2b(f3w[j]); continue; } j -= 16384;
      int tt = j >> 12, rem = j & 4095, co = rem >> 6, ci = rem & 63;
      f2p[j] = f2b(f2w[(co * 64 + ci) * 9 + tt]);
    }
  }
}

// ---------------------------------------------------------------------------
// proj: R2 2-tile (best measured). Grid (25,6,BB).
// ---------------------------------------------------------------------------
__global__ __launch_bounds__(256) void proj_kernel(
    const u16* __restrict__ xt,
    const u16* __restrict__ gwb, const u16* __restrict__ twb, const u16* __restrict__ pwb,
    const float* __restrict__ gb, const float* __restrict__ tb, const float* __restrict__ pb,
    u16* __restrict__ gx, u16* __restrict__ Tq, u16* __restrict__ Pk) {
  const int b = blockIdx.z, oc = blockIdx.y, nb = blockIdx.x * 128;
  const int sec = oc >> 1, rbase = (oc & 1) * 64;
  const u16* wsel = sec == 0 ? gwb : (sec == 1 ? twb : pwb);
  const float* bsel = sec == 0 ? gb : (sec == 1 ? tb : pb);
  const int wv = threadIdx.x >> 6, lane = threadIdx.x & 63;
  const int lr = lane & 15, lq = lane >> 4;
  const int nrow0 = nb + wv * 32, nrow1 = nrow0 + 16;
  const int r0 = nrow0 + lr < NPIX ? nrow0 + lr : NPIX - 1;
  const int r1 = nrow1 + lr < NPIX ? nrow1 + lr : NPIX - 1;
  f32x4 acc[8] = {};
  mf_gemm2<8, 4>(xt + ((size_t)b * NPIX + r0) * 256,
                 xt + ((size_t)b * NPIX + r1) * 256,
                 wsel + (size_t)(rbase + lr) * 256, 256, lq, acc);
#pragma unroll
  for (int t = 0; t < 2; ++t) {
    const int qn = (t ? nrow1 : nrow0) + lq * 4;
    if (qn >= NPIX) continue;
#pragma unroll
    for (int ot = 0; ot < 4; ++ot) {
      const f32x4 a = acc[t * 4 + ot];
      const int o = rbase + ot * 16 + lr;
      float bias = bsel[o];
      if (sec == 1) bias *= LOG2E;
      if (sec == 0) {
        uint2 s;
        s.x = pk2(a[0] + bias, a[1] + bias);
        s.y = pk2(a[2] + bias, a[3] + bias);
        *(uint2*)(gx + ((size_t)b * 128 + o) * NPIX + qn) = s;
      } else {
        const int g = o >> 5, dl = o & 31;
        u16* dst = sec == 1 ? Tq : Pk;
        size_t base = (size_t)(b * 4 + g) * NPIX;
#pragma unroll
        for (int r = 0; r < 4; ++r)
          dst[(base + qn + r) * 32 + dl] = f2b(a[r] + bias);
      }
    }
  }
}

// ---------------------------------------------------------------------------
// attn: R12 form (best measured: 66.0us, plateau confirmed over R13/R14).
// ---------------------------------------------------------------------------
__global__ __launch_bounds__(256) void attn_kernel(
    const u16* __restrict__ Tq, const u16* __restrict__ Pk,
    const u16* __restrict__ gx, u16* __restrict__ OPb, float* __restrict__ LP) {
  __shared__ __align__(16) u16 Plds[4][32][40];
  const int bid = blockIdx.x;
  const int ks = bid / 400, rem = bid % 400;
  const int bg = rem / 25, qblk = rem % 25;
  const int b = bg >> 2, g = bg & 3;
  const int wave = threadIdx.x >> 6, lane = threadIdx.x & 63;
  const int lr = lane & 15, lq = lane >> 4;
  const int qbase = qblk * 128 + wave * 32;
  const int kc0 = ((ks * 98) / NSPLIT) * 32;
  const int kc1 = (((ks + 1) * 98) / NSPLIT) * 32;
  const u16* Qp = Tq + (size_t)bg * NPIX * 32;
  const u16* Kp = Pk + (size_t)bg * NPIX * 32;
  const u16* Vp = gx + ((size_t)b * 128 + g * 32) * NPIX;

  bf16x8 qf[2];
#pragma unroll
  for (int qi = 0; qi < 2; ++qi) {
    int row = qbase + qi * 16 + lr;
    row = row < NPIX ? row : NPIX - 1;
    qf[qi] = *(const bf16x8*)(Qp + (size_t)row * 32 + lq * 8);
  }
  const f32x4 z4 = {0.f, 0.f, 0.f, 0.f};
  f32x4 O[2][2], Lf[2];
#pragma unroll
  for (int qi = 0; qi < 2; ++qi) { O[qi][0] = z4; O[qi][1] = z4; Lf[qi] = z4; }
  bf16x8 onef;
#pragma unroll
  for (int j = 0; j < 8; ++j) onef[j] = (__bf16)1.0f;

#pragma unroll 1
  for (int kc = kc0; kc < kc1; kc += 32) {
    bf16x8 kf0 = *(const bf16x8*)(Kp + (size_t)(kc + lr) * 32 + lq * 8);
    bf16x8 kf1 = *(const bf16x8*)(Kp + (size_t)(kc + 16 + lr) * 32 + lq * 8);
    // Swapped operands: St[kt][qi] lane(lq,lr) reg r =
    //   score(k = kc + kt*16 + lq*4 + r, q = qbase + qi*16 + lr)
    f32x4 St[2][2];
    St[0][0] = mfma(kf0, qf[0], z4);
    St[0][1] = mfma(kf0, qf[1], z4);
    St[1][0] = mfma(kf1, qf[0], z4);
    St[1][1] = mfma(kf1, qf[1], z4);
#pragma unroll
    for (int kt = 0; kt < 2; ++kt)
#pragma unroll
      for (int qi = 0; qi < 2; ++qi) {
        const f32x4 s = St[kt][qi];
        unsigned e0 = __builtin_bit_cast(unsigned, fast_exp2(s[0]));
        unsigned e1 = __builtin_bit_cast(unsigned, fast_exp2(s[1]));
        unsigned e2 = __builtin_bit_cast(unsigned, fast_exp2(s[2]));
        unsigned e3 = __builtin_bit_cast(unsigned, fast_exp2(s[3]));
        uint2 pk;  // [bf16(e0),bf16(e1)] , [bf16(e2),bf16(e3)] (high-16 trunc)
        pk.x = __builtin_amdgcn_perm(e1, e0, 0x07060302u);
        pk.y = __builtin_amdgcn_perm(e3, e2, 0x07060302u);
        *(uint2*)(&Plds[wave][qi * 16 + lr][kt * 16 + lq * 4]) = pk;
      }
    bf16x8 pf0 = *(const bf16x8*)(&Plds[wave][lr][lq * 8]);
    bf16x8 pf1 = *(const bf16x8*)(&Plds[wave][16 + lr][lq * 8]);
    bf16x8 vf0 = *(const bf16x8*)(Vp + (size_t)lr * NPIX + kc + lq * 8);
    bf16x8 vf1 = *(const bf16x8*)(Vp + (size_t)(16 + lr) * NPIX + kc + lq * 8);
    O[0][0] = mfma(pf0, vf0, O[0][0]);
    O[0][1] = mfma(pf0, vf1, O[0][1]);
    O[1][0] = mfma(pf1, vf0, O[1][0]);
    O[1][1] = mfma(pf1, vf1, O[1][1]);
    Lf[0] = mfma(pf0, onef, Lf[0]);
    Lf[1] = mfma(pf1, onef, Lf[1]);
  }
  const size_t sbase = (size_t)(ks * 16 + bg) * NPIX;
#pragma unroll
  for (int qi = 0; qi < 2; ++qi) {
#pragma unroll
    for (int r = 0; r < 4; ++r) {
      int qrow = qbase + qi * 16 + lq * 4 + r;
      if (qrow < NPIX) {
        size_t ob = (sbase + qrow) * 32;
        OPb[ob + lr] = f2b(O[qi][0][r]);
        OPb[ob + 16 + lr] = f2b(O[qi][1][r]);
        if (lr == 0) LP[sbase + qrow] = Lf[qi][r];
      }
    }
  }
}

// ---------------------------------------------------------------------------
// wz+ff1 fused (R16, verified -13us): phase 1 = R2 wz -> zt + LDS z-tile;
// phase 2 = ff1 (8 MFMAs/wave from LDS) -> o1t.
// ---------------------------------------------------------------------------
__global__ __launch_bounds__(512) void wz_kernel(
    const u16* __restrict__ OPb, const float* __restrict__ LP,
    const u16* __restrict__ Wwb, const float* __restrict__ Wb,
    const float* __restrict__ sc, const float* __restrict__ bi,
    const float* __restrict__ mu, const float* __restrict__ var,
    const float* __restrict__ x,
    const u16* __restrict__ f1b, const float* __restrict__ s1,
    const float* __restrict__ b1, const float* __restrict__ m1,
    const float* __restrict__ v1,
    u16* __restrict__ zt, u16* __restrict__ o1t) {
  __shared__ float Ls[4][32];
  __shared__ __align__(16) u16 zl[32 * ZLS];
  const int b = blockIdx.y, nb = blockIdx.x * 32;
  const int tid = threadIdx.x;
  if (tid < 128) {
    int g = tid >> 5, row = tid & 31;
    float l = 0.f;
#pragma unroll
    for (int ks = 0; ks < NSPLIT; ++ks)
      l += LP[(size_t)(ks * 16 + b * 4 + g) * NPIX + nb + row];
    Ls[g][row] = 1.0f / l;
  }
  __syncthreads();
  const int wave = tid >> 6, lane = tid & 63;
  const int lr = lane & 15, lq = lane >> 4;
  const int oc = wave & 3, tt = wave >> 2;
  const int nrow = nb + tt * 16;
  f32x4 acc[4][4] = {};                // [g][ot]
#pragma unroll
  for (int g = 0; g < 4; ++g) {
    bf16x8 bf[4];
#pragma unroll
    for (int ot = 0; ot < 4; ++ot)
      bf[ot] = *(const bf16x8*)(Wwb + (size_t)(oc * 64 + ot * 16 + lr) * 128 + g * 32 + lq * 8);
#pragma unroll
    for (int ks = 0; ks < NSPLIT; ++ks) {
      bf16x8 af = *(const bf16x8*)(OPb +
          ((size_t)(ks * 16 + b * 4 + g) * NPIX + nrow + lr) * 32 + lq * 8);
#pragma unroll
      for (int ot = 0; ot < 4; ++ot)
        acc[g][ot] = mfma(af, bf[ot], acc[g][ot]);
    }
  }
#pragma unroll
  for (int ot = 0; ot < 4; ++ot) {
    const int o = oc * 64 + ot * 16 + lr;
    float inv = sc[o] * rsqrtf(var[o] + 1e-5f);
    float off = bi[o] - mu[o] * inv + Wb[o] * inv;
    const int qn = nrow + lq * 4;
    float4 xr = *(const float4*)(x + ((size_t)b * 256 + o) * NPIX + qn);
    float xv[4] = {xr.x, xr.y, xr.z, xr.w};
#pragma unroll
    for (int r = 0; r < 4; ++r) {
      int row = tt * 16 + lq * 4 + r;
      float y = acc[0][ot][r] * Ls[0][row] + acc[1][ot][r] * Ls[1][row] +
                acc[2][ot][r] * Ls[2][row] + acc[3][ot][r] * Ls[3][row];
      float v = fmaxf(y * inv + off + xv[r], 0.f);
      u16 vb = f2b(v);
      zt[((size_t)b * NPIX + qn + r) * 256 + o] = vb;
      zl[row * ZLS + o] = vb;
    }
  }
  __syncthreads();
  // ---- phase 2: ff1. Wave (tt2,oc2): 16 rows x 16 out-ch, K=256 from LDS.
  const int oc2 = wave & 3, tt2 = wave >> 2;
  f32x4 a1 = {0.f, 0.f, 0.f, 0.f};
  const u16* Bw = f1b + (size_t)(oc2 * 16 + lr) * 256;
#pragma unroll
  for (int s = 0; s < 8; ++s) {
    bf16x8 a0 = *(const bf16x8*)(&zl[(tt2 * 16 + lr) * ZLS + s * 32 + lq * 8]);
    bf16x8 bw = *(const bf16x8*)(Bw + s * 32 + lq * 8);
    a1 = mfma(a0, bw, a1);
  }
  const int o1 = oc2 * 16 + lr;
  float inv1 = s1[o1] * rsqrtf(v1[o1] + 1e-5f);
  float off1 = b1[o1] - m1[o1] * inv1;
  const int pr = nb + tt2 * 16 + lq * 4;
#pragma unroll
  for (int r = 0; r < 4; ++r) {
    float v = fmaxf(a1[r] * inv1 + off1, 0.f);
    o1t[((size_t)b * NPIX + pr + r) * 64 + o1] = f2b(v);
  }
}

// ---------------------------------------------------------------------------
// ff2: R2 2-tile im2col MFMA. Grid (25,2,BB).
// ---------------------------------------------------------------------------
__global__ __launch_bounds__(256) void ff2_kernel(
    const u16* __restrict__ o1t, const u16* __restrict__ f2p,
    const float* __restrict__ sc, const float* __restrict__ bi,
    const float* __restrict__ mu, const float* __restrict__ var,
    u16* __restrict__ o2t) {
  const int b = blockIdx.z, oc = blockIdx.y, nb = blockIdx.x * 128;
  const int wv = threadIdx.x >> 6, lane = threadIdx.x & 63;
  const int lr = lane & 15, lq = lane >> 4;
  const int n0 = nb + wv * 32 + lr, n1 = n0 + 16;
  const int h0 = n0 / 56, w0 = n0 % 56;
  const int h1 = n1 / 56, w1 = n1 % 56;
  f32x4 acc[4] = {};
#pragma unroll
  for (int t = 0; t < 9; ++t) {
    const int dh = t / 3 - 1, dw = t % 3 - 1;
    const bool v0 = (h0 + dh) >= 0 && (h0 + dh) < 56 && (w0 + dw) >= 0 && (w0 + dw) < 56;
    const bool v1 = (h1 + dh) >= 0 && (h1 + dh) < 56 && (w1 + dw) >= 0 && (w1 + dw) < 56;
    const u16* A0 = o1t + ((size_t)b * NPIX + n0 + dh * 56 + dw) * 64;
    const u16* A1 = o1t + ((size_t)b * NPIX + n1 + dh * 56 + dw) * 64;
    const u16* Br = f2p + (size_t)t * 4096 + (size_t)(oc * 32 + lr) * 64;
#pragma unroll
    for (int k2 = 0; k2 < 2; ++k2) {
      bf16x8 bf0 = *(const bf16x8*)(Br + k2 * 32 + lq * 8);
      bf16x8 bf1 = *(const bf16x8*)(Br + (size_t)16 * 64 + k2 * 32 + lq * 8);
      bf16x8 a0 = {}, a1 = {};
      if (v0) a0 = *(const bf16x8*)(A0 + k2 * 32 + lq * 8);
      if (v1) a1 = *(const bf16x8*)(A1 + k2 * 32 + lq * 8);
      acc[0] = mfma(a0, bf0, acc[0]);
      acc[1] = mfma(a0, bf1, acc[1]);
      acc[2] = mfma(a1, bf0, acc[2]);
      acc[3] = mfma(a1, bf1, acc[3]);
    }
  }
  const int nrow0 = nb + wv * 32;
#pragma unroll
  for (int t = 0; t < 2; ++t) {
    const int qn = nrow0 + t * 16 + lq * 4;
    if (qn >= NPIX) continue;
#pragma unroll
    for (int ot = 0; ot < 2; ++ot) {
      const f32x4 a = acc[t * 2 + ot];
      const int o = oc * 32 + ot * 16 + lr;
      float inv = sc[o] * rsqrtf(var[o] + 1e-5f);
      float off = bi[o] - mu[o] * inv;
#pragma unroll
      for (int r = 0; r < 4; ++r) {
        float v = fmaxf(a[r] * inv + off, 0.f);
        o2t[((size_t)b * NPIX + qn + r) * 64 + o] = f2b(v);
      }
    }
  }
}

// ---------------------------------------------------------------------------
// ff3: R2 2-tile. Grid (25,4,BB).
// ---------------------------------------------------------------------------
__global__ __launch_bounds__(256) void ff3_kernel(
    const u16* __restrict__ o2t, const u16* __restrict__ f3b,
    const float* __restrict__ sc, const float* __restrict__ bi,
    const float* __restrict__ mu, const float* __restrict__ var,
    const u16* __restrict__ zt, float* __restrict__ out) {
  const int b = blockIdx.z, oc = blockIdx.y, nb = blockIdx.x * 128;
  const int wv = threadIdx.x >> 6, lane = threadIdx.x & 63;
  const int lr = lane & 15, lq = lane >> 4;
  const int nrow0 = nb + wv * 32, nrow1 = nrow0 + 16;
  const int r0 = nrow0 + lr < NPIX ? nrow0 + lr : NPIX - 1;
  const int r1 = nrow1 + lr < NPIX ? nrow1 + lr : NPIX - 1;
  f32x4 acc[8] = {};
  mf_gemm2<2, 4>(o2t + ((size_t)b * NPIX + r0) * 64,
                 o2t + ((size_t)b * NPIX + r1) * 64,
                 f3b + (size_t)(oc * 64 + lr) * 64, 64, lq, acc);
#pragma unroll
  for (int t = 0; t < 2; ++t) {
    const int qn = (t ? nrow1 : nrow0) + lq * 4;
    if (qn >= NPIX) continue;
#pragma unroll
    for (int ot = 0; ot < 4; ++ot) {
      const f32x4 a = acc[t * 4 + ot];
      const int o = oc * 64 + ot * 16 + lr;
      float inv = sc[o] * rsqrtf(var[o] + 1e-5f);
      float off = bi[o] - mu[o] * inv;
      float4 s;
      float* sv = (float*)&s;
#pragma unroll
      for (int r = 0; r < 4; ++r) {
        float zres = b2f(zt[((size_t)b * NPIX + qn + r) * 256 + o]);
        sv[r] = fmaxf(a[r] * inv + off + zres, 0.f);
      }
      *(float4*)(out + ((size_t)b * 256 + o) * NPIX + qn) = s;
    }
  }
}

// ---------------------------------------------------------------------------
extern "C" void kernel_launch(void* const* d_in, const int* in_sizes, int n_in,
                              void* d_out, int out_size, void* d_ws, size_t ws_size,
                              hipStream_t stream) {
  const float* x    = (const float*)d_in[0];
  const float* gw   = (const float*)d_in[1];
  const float* gb   = (const float*)d_in[2];
  const float* tw   = (const float*)d_in[3];
  const float* tb   = (const float*)d_in[4];
  const float* pw   = (const float*)d_in[5];
  const float* pb   = (const float*)d_in[6];
  const float* Ww   = (const float*)d_in[7];
  const float* Wb   = (const float*)d_in[8];
  const float* bnWs = (const float*)d_in[9];
  const float* bnWb = (const float*)d_in[10];
  const float* bnWm = (const float*)d_in[11];
  const float* bnWv = (const float*)d_in[12];
  const float* f1w  = (const float*)d_in[13];
  const float* b1s  = (const float*)d_in[14];
  const float* b1b  = (const float*)d_in[15];
  const float* b1m  = (const float*)d_in[16];
  const float* b1v  = (const float*)d_in[17];
  const float* f2w  = (const float*)d_in[18];
  const float* b2s  = (const float*)d_in[19];
  const float* b2b  = (const float*)d_in[20];
  const float* b2m  = (const float*)d_in[21];
  const float* b2v  = (const float*)d_in[22];
  const float* f3w  = (const float*)d_in[23];
  const float* b3s  = (const float*)d_in[24];
  const float* b3b  = (const float*)d_in[25];
  const float* b3m  = (const float*)d_in[26];
  const float* b3v  = (const float*)d_in[27];
  float* out = (float*)d_out;

  u16* p = (u16*)d_ws;
  u16* xt  = p; p += (size_t)BB * NPIX * 256;
  u16* gwb = p; p += 128 * 256;
  u16* twb = p; p += 128 * 256;
  u16* pwb = p; p += 128 * 256;
  u16* Wwb = p; p += 256 * 128;
  u16* f1b = p; p += 64 * 256;
  u16* f3b = p; p += 256 * 64;
  u16* f2p = p; p += 9 * 64 * 64;
  u16* Tq  = p; p += (size_t)16 * NPIX * 32;
  u16* Pk  = p; p += (size_t)16 * NPIX * 32;
  u16* gx  = p; p += (size_t)BB * 128 * NPIX;
  u16* OPb = p; p += (size_t)7 * 16 * NPIX * 32;   // bump kept at 7 (upper bound)
  float* LP = (float*)p; p += (size_t)7 * 16 * NPIX * 2;
  u16* zt  = p; p += (size_t)BB * NPIX * 256;
  u16* o1t = p; p += (size_t)BB * NPIX * 64;
  u16* o2t = p; p += (size_t)BB * NPIX * 64;

  prep_all<<<dim3(980), 256, 0, stream>>>(x, gw, tw, pw, Ww, f1w, f2w, f3w,
                                          xt, gwb, twb, pwb, Wwb, f1b, f3b, f2p);
  proj_kernel<<<dim3(25, 6, BB), 256, 0, stream>>>(xt, gwb, twb, pwb, gb, tb, pb,
                                                   gx, Tq, Pk);
  attn_kernel<<<dim3(NSPLIT * 400), 256, 0, stream>>>(Tq, Pk, gx, OPb, LP);
  wz_kernel<<<dim3(98, BB), 512, 0, stream>>>(OPb, LP, Wwb, Wb,
                                              bnWs, bnWb, bnWm, bnWv, x,
                                              f1b, b1s, b1b, b1m, b1v,
                                              zt, o1t);
  ff1_unused:;
  ff2_kernel<<<dim3(25, 2, BB), 256, 0, stream>>>(o1t, f2p, b2s, b2b, b2m, b2v, o2t);
  ff3_kernel<<<dim3(25, 4, BB), 256, 0, stream>>>(o2t, f3b, b3s, b3b, b3m, b3v, zt, out);
}

// Round 10
// 235.854 us; speedup vs baseline: 1.0653x; 1.0086x over previous
//
#include <hip/hip_runtime.h>
#include <hip/hip_bf16.h>

#define NPIX 3136
#define BB 4
#define NSPLIT 3
#define LOG2E 1.4426950408889634f
#define ZLS 264  // LDS z-tile stride in u16 (wz+ff1 fusion)

typedef unsigned short u16;
typedef __bf16 bf16x8 __attribute__((ext_vector_type(8)));
typedef float f32x4 __attribute__((ext_vector_type(4)));

__device__ __forceinline__ float b2f(u16 u) {
  union { unsigned u; float f; } c; c.u = ((unsigned)u) << 16; return c.f;
}
__device__ __forceinline__ u16 f2b(float f) {
  __hip_bfloat16 h = __float2bfloat16(f);
  return *reinterpret_cast<u16*>(&h);
}
__device__ __forceinline__ unsigned pk2(float a, float b) {
  return (unsigned)f2b(a) | ((unsigned)f2b(b) << 16);
}
__device__ __forceinline__ f32x4 mfma(bf16x8 a, bf16x8 b, f32x4 c) {
  return __builtin_amdgcn_mfma_f32_16x16x32_bf16(a, b, c, 0, 0, 0);
}
// Raw v_exp_f32: scores are |x| << 126 so the compiler's denormal-guard
// expansion (~5 VALU ops) around llvm.exp2 is dead weight.
__device__ __forceinline__ float fast_exp2(float x) {
#if __has_builtin(__builtin_amdgcn_exp2f)
  return __builtin_amdgcn_exp2f(x);
#else
  float r; asm("v_exp_f32 %0, %1" : "=v"(r) : "v"(x)); return r;
#endif
}

// ---------------------------------------------------------------------------
// 2-tile MFMA wave-GEMM (R10/R2 shape -- best measured for proj/ff2/ff3).
// ---------------------------------------------------------------------------
template<int NSTEP, int NOT>
__device__ __forceinline__ void mf_gemm2(const u16* __restrict__ A0,
                                         const u16* __restrict__ A1,
                                         const u16* __restrict__ Brow, int sB,
                                         int lq, f32x4* acc) {
#pragma unroll
  for (int s = 0; s < NSTEP; ++s) {
    bf16x8 bf[NOT];
#pragma unroll
    for (int ot = 0; ot < NOT; ++ot)
      bf[ot] = *(const bf16x8*)(Brow + (size_t)ot * 16 * sB + s * 32 + lq * 8);
    bf16x8 a0 = *(const bf16x8*)(A0 + s * 32 + lq * 8);
    bf16x8 a1 = *(const bf16x8*)(A1 + s * 32 + lq * 8);
#pragma unroll
    for (int ot = 0; ot < NOT; ++ot) {
      acc[ot] = mfma(a0, bf[ot], acc[ot]);
      acc[NOT + ot] = mfma(a1, bf[ot], acc[NOT + ot]);
    }
  }
}

// ---------------------------------------------------------------------------
// prep_all (R19, neutral-kept): prep_x (blocks 0..783) + prep_w (784..979).
// ---------------------------------------------------------------------------
__global__ __launch_bounds__(256) void prep_all(
    const float* __restrict__ x,
    const float* __restrict__ gw, const float* __restrict__ tw,
    const float* __restrict__ pw, const float* __restrict__ Ww,
    const float* __restrict__ f1w, const float* __restrict__ f2w,
    const float* __restrict__ f3w,
    u16* __restrict__ xt,
    u16* __restrict__ gwb, u16* __restrict__ twb, u16* __restrict__ pwb,
    u16* __restrict__ Wwb, u16* __restrict__ f1b, u16* __restrict__ f3b,
    u16* __restrict__ f2p) {
  __shared__ u16 sT[64 * 65];
  const int bid = blockIdx.x;
  const int t = threadIdx.x;
  if (bid < 784) {
    const int b = bid / 196, rem = bid % 196;
    const int c0 = (rem / 49) * 64, n0 = (rem % 49) * 64;
#pragma unroll
    for (int cc = 0; cc < 4; ++cc) {
      int c = cc * 16 + (t >> 4), n4 = (t & 15) * 4;
      float4 v = *(const float4*)(x + ((size_t)(b * 256 + c0 + c)) * NPIX + n0 + n4);
      sT[c * 65 + n4 + 0] = f2b(v.x);
      sT[c * 65 + n4 + 1] = f2b(v.y);
      sT[c * 65 + n4 + 2] = f2b(v.z);
      sT[c * 65 + n4 + 3] = f2b(v.w);
    }
    __syncthreads();
#pragma unroll
    for (int nn = 0; nn < 4; ++nn) {
      int n = nn * 16 + (t >> 4), c4 = (t & 15) * 4;
      uint2 s;
      s.x = (unsigned)sT[(c4 + 0) * 65 + n] | ((unsigned)sT[(c4 + 1) * 65 + n] << 16);
      s.y = (unsigned)sT[(c4 + 2) * 65 + n] | ((unsigned)sT[(c4 + 3) * 65 + n] << 16);
      *(uint2*)(xt + ((size_t)b * NPIX + n0 + n) * 256 + c0 + c4) = s;
    }
  } else {
    for (int i = (bid - 784) * 256 + t; i < 200704; i += 196 * 256) {
      int j = i;
      if (j < 32768) { gwb[j] = f2b(gw[j]); continue; } j -= 32768;
      if (j < 32768) { twb[j] = f2b(tw[j] * LOG2E); continue; } j -= 32768;
      if (j < 32768) { pwb[j] = f2b(pw[j]); continue; } j -= 32768;
      if (j < 32768) { Wwb[j] = f2b(Ww[j]); continue; } j -= 32768;
      if (j < 16384) { f1b[j] = f2b(f1w[j]); continue; } j -= 16384;
      if (j < 16384) { f3b[j] = f2b(f3w[j]); continue; } j -= 16384;
      int tt = j >> 12, rem = j & 4095, co = rem >> 6, ci = rem & 63;
      f2p[j] = f2b(f2w[(co * 64 + ci) * 9 + tt]);
    }
  }
}

// ---------------------------------------------------------------------------
// proj: R2 2-tile (best measured). Grid (25,6,BB).
// ---------------------------------------------------------------------------
__global__ __launch_bounds__(256) void proj_kernel(
    const u16* __restrict__ xt,
    const u16* __restrict__ gwb, const u16* __restrict__ twb, const u16* __restrict__ pwb,
    const float* __restrict__ gb, const float* __restrict__ tb, const float* __restrict__ pb,
    u16* __restrict__ gx, u16* __restrict__ Tq, u16* __restrict__ Pk) {
  const int b = blockIdx.z, oc = blockIdx.y, nb = blockIdx.x * 128;
  const int sec = oc >> 1, rbase = (oc & 1) * 64;
  const u16* wsel = sec == 0 ? gwb : (sec == 1 ? twb : pwb);
  const float* bsel = sec == 0 ? gb : (sec == 1 ? tb : pb);
  const int wv = threadIdx.x >> 6, lane = threadIdx.x & 63;
  const int lr = lane & 15, lq = lane >> 4;
  const int nrow0 = nb + wv * 32, nrow1 = nrow0 + 16;
  const int r0 = nrow0 + lr < NPIX ? nrow0 + lr : NPIX - 1;
  const int r1 = nrow1 + lr < NPIX ? nrow1 + lr : NPIX - 1;
  f32x4 acc[8] = {};
  mf_gemm2<8, 4>(xt + ((size_t)b * NPIX + r0) * 256,
                 xt + ((size_t)b * NPIX + r1) * 256,
                 wsel + (size_t)(rbase + lr) * 256, 256, lq, acc);
#pragma unroll
  for (int t = 0; t < 2; ++t) {
    const int qn = (t ? nrow1 : nrow0) + lq * 4;
    if (qn >= NPIX) continue;
#pragma unroll
    for (int ot = 0; ot < 4; ++ot) {
      const f32x4 a = acc[t * 4 + ot];
      const int o = rbase + ot * 16 + lr;
      float bias = bsel[o];
      if (sec == 1) bias *= LOG2E;
      if (sec == 0) {
        uint2 s;
        s.x = pk2(a[0] + bias, a[1] + bias);
        s.y = pk2(a[2] + bias, a[3] + bias);
        *(uint2*)(gx + ((size_t)b * 128 + o) * NPIX + qn) = s;
      } else {
        const int g = o >> 5, dl = o & 31;
        u16* dst = sec == 1 ? Tq : Pk;
        size_t base = (size_t)(b * 4 + g) * NPIX;
#pragma unroll
        for (int r = 0; r < 4; ++r)
          dst[(base + qn + r) * 32 + dl] = f2b(a[r] + bias);
      }
    }
  }
}

// ---------------------------------------------------------------------------
// attn R20: NSPLIT=3 (1200 blocks = 2 rounds at ~3 blocks/CU concurrency;
// rounds model fit to N=5/N=7 measurements predicts 60.2us vs 65.4) +
// vectorized epilogue: O transposed through the free Plds buffer (16 LDS
// u16 writes + 2 ds_read_b128) -> 2 coalesced dwordx4 stores per lane
// (was 16 scattered scalar u16 global stores, ~256 segments/wave).
// ---------------------------------------------------------------------------
__global__ __launch_bounds__(256) void attn_kernel(
    const u16* __restrict__ Tq, const u16* __restrict__ Pk,
    const u16* __restrict__ gx, u16* __restrict__ OPb, float* __restrict__ LP) {
  __shared__ __align__(16) u16 Plds[4][32][40];
  const int bid = blockIdx.x;
  const int ks = bid / 400, rem = bid % 400;
  const int bg = rem / 25, qblk = rem % 25;
  const int b = bg >> 2, g = bg & 3;
  const int wave = threadIdx.x >> 6, lane = threadIdx.x & 63;
  const int lr = lane & 15, lq = lane >> 4;
  const int qbase = qblk * 128 + wave * 32;
  const int kc0 = ((ks * 98) / NSPLIT) * 32;
  const int kc1 = (((ks + 1) * 98) / NSPLIT) * 32;
  const u16* Qp = Tq + (size_t)bg * NPIX * 32;
  const u16* Kp = Pk + (size_t)bg * NPIX * 32;
  const u16* Vp = gx + ((size_t)b * 128 + g * 32) * NPIX;

  bf16x8 qf[2];
#pragma unroll
  for (int qi = 0; qi < 2; ++qi) {
    int row = qbase + qi * 16 + lr;
    row = row < NPIX ? row : NPIX - 1;
    qf[qi] = *(const bf16x8*)(Qp + (size_t)row * 32 + lq * 8);
  }
  const f32x4 z4 = {0.f, 0.f, 0.f, 0.f};
  f32x4 O[2][2], Lf[2];
#pragma unroll
  for (int qi = 0; qi < 2; ++qi) { O[qi][0] = z4; O[qi][1] = z4; Lf[qi] = z4; }
  bf16x8 onef;
#pragma unroll
  for (int j = 0; j < 8; ++j) onef[j] = (__bf16)1.0f;

#pragma unroll 1
  for (int kc = kc0; kc < kc1; kc += 32) {
    bf16x8 kf0 = *(const bf16x8*)(Kp + (size_t)(kc + lr) * 32 + lq * 8);
    bf16x8 kf1 = *(const bf16x8*)(Kp + (size_t)(kc + 16 + lr) * 32 + lq * 8);
    // Swapped operands: St[kt][qi] lane(lq,lr) reg r =
    //   score(k = kc + kt*16 + lq*4 + r, q = qbase + qi*16 + lr)
    f32x4 St[2][2];
    St[0][0] = mfma(kf0, qf[0], z4);
    St[0][1] = mfma(kf0, qf[1], z4);
    St[1][0] = mfma(kf1, qf[0], z4);
    St[1][1] = mfma(kf1, qf[1], z4);
#pragma unroll
    for (int kt = 0; kt < 2; ++kt)
#pragma unroll
      for (int qi = 0; qi < 2; ++qi) {
        const f32x4 s = St[kt][qi];
        unsigned e0 = __builtin_bit_cast(unsigned, fast_exp2(s[0]));
        unsigned e1 = __builtin_bit_cast(unsigned, fast_exp2(s[1]));
        unsigned e2 = __builtin_bit_cast(unsigned, fast_exp2(s[2]));
        unsigned e3 = __builtin_bit_cast(unsigned, fast_exp2(s[3]));
        uint2 pk;  // [bf16(e0),bf16(e1)] , [bf16(e2),bf16(e3)] (high-16 trunc)
        pk.x = __builtin_amdgcn_perm(e1, e0, 0x07060302u);
        pk.y = __builtin_amdgcn_perm(e3, e2, 0x07060302u);
        *(uint2*)(&Plds[wave][qi * 16 + lr][kt * 16 + lq * 4]) = pk;
      }
    bf16x8 pf0 = *(const bf16x8*)(&Plds[wave][lr][lq * 8]);
    bf16x8 pf1 = *(const bf16x8*)(&Plds[wave][16 + lr][lq * 8]);
    bf16x8 vf0 = *(const bf16x8*)(Vp + (size_t)lr * NPIX + kc + lq * 8);
    bf16x8 vf1 = *(const bf16x8*)(Vp + (size_t)(16 + lr) * NPIX + kc + lq * 8);
    O[0][0] = mfma(pf0, vf0, O[0][0]);
    O[0][1] = mfma(pf0, vf1, O[0][1]);
    O[1][0] = mfma(pf1, vf0, O[1][0]);
    O[1][1] = mfma(pf1, vf1, O[1][1]);
    Lf[0] = mfma(pf0, onef, Lf[0]);
    Lf[1] = mfma(pf1, onef, Lf[1]);
  }
  const size_t sbase = (size_t)(ks * 16 + bg) * NPIX;
  // LP from registers (unchanged layout).
  if (lr == 0) {
#pragma unroll
    for (int qi = 0; qi < 2; ++qi)
#pragma unroll
      for (int r = 0; r < 4; ++r) {
        int qrow = qbase + qi * 16 + lq * 4 + r;
        if (qrow < NPIX) LP[sbase + qrow] = Lf[qi][r];
      }
  }
  // O -> Plds (reused, per-wave, no barrier) -> coalesced 16B stores.
#pragma unroll
  for (int qi = 0; qi < 2; ++qi)
#pragma unroll
    for (int t = 0; t < 2; ++t)
#pragma unroll
      for (int r = 0; r < 4; ++r)
        Plds[wave][qi * 16 + lq * 4 + r][t * 16 + lr] = f2b(O[qi][t][r]);
#pragma unroll
  for (int ps = 0; ps < 2; ++ps) {
    const int row = ps * 16 + (lane >> 2);
    const int c8 = (lane & 3) * 8;
    const int qrow = qbase + row;
    uint4 v = *(const uint4*)(&Plds[wave][row][c8]);
    if (qrow < NPIX)
      *(uint4*)(&OPb[(sbase + qrow) * 32 + c8]) = v;
  }
}

// ---------------------------------------------------------------------------
// wz+ff1 fused (R16, verified -13us): phase 1 = wz (NSPLIT partials) ->
// zt + LDS z-tile; phase 2 = ff1 (8 MFMAs/wave from LDS) -> o1t.
// ---------------------------------------------------------------------------
__global__ __launch_bounds__(512) void wz_kernel(
    const u16* __restrict__ OPb, const float* __restrict__ LP,
    const u16* __restrict__ Wwb, const float* __restrict__ Wb,
    const float* __restrict__ sc, const float* __restrict__ bi,
    const float* __restrict__ mu, const float* __restrict__ var,
    const float* __restrict__ x,
    const u16* __restrict__ f1b, const float* __restrict__ s1,
    const float* __restrict__ b1, const float* __restrict__ m1,
    const float* __restrict__ v1,
    u16* __restrict__ zt, u16* __restrict__ o1t) {
  __shared__ float Ls[4][32];
  __shared__ __align__(16) u16 zl[32 * ZLS];
  const int b = blockIdx.y, nb = blockIdx.x * 32;
  const int tid = threadIdx.x;
  if (tid < 128) {
    int g = tid >> 5, row = tid & 31;
    float l = 0.f;
#pragma unroll
    for (int ks = 0; ks < NSPLIT; ++ks)
      l += LP[(size_t)(ks * 16 + b * 4 + g) * NPIX + nb + row];
    Ls[g][row] = 1.0f / l;
  }
  __syncthreads();
  const int wave = tid >> 6, lane = tid & 63;
  const int lr = lane & 15, lq = lane >> 4;
  const int oc = wave & 3, tt = wave >> 2;
  const int nrow = nb + tt * 16;
  f32x4 acc[4][4] = {};                // [g][ot]
#pragma unroll
  for (int g = 0; g < 4; ++g) {
    bf16x8 bf[4];
#pragma unroll
    for (int ot = 0; ot < 4; ++ot)
      bf[ot] = *(const bf16x8*)(Wwb + (size_t)(oc * 64 + ot * 16 + lr) * 128 + g * 32 + lq * 8);
#pragma unroll
    for (int ks = 0; ks < NSPLIT; ++ks) {
      bf16x8 af = *(const bf16x8*)(OPb +
          ((size_t)(ks * 16 + b * 4 + g) * NPIX + nrow + lr) * 32 + lq * 8);
#pragma unroll
      for (int ot = 0; ot < 4; ++ot)
        acc[g][ot] = mfma(af, bf[ot], acc[g][ot]);
    }
  }
#pragma unroll
  for (int ot = 0; ot < 4; ++ot) {
    const int o = oc * 64 + ot * 16 + lr;
    float inv = sc[o] * rsqrtf(var[o] + 1e-5f);
    float off = bi[o] - mu[o] * inv + Wb[o] * inv;
    const int qn = nrow + lq * 4;
    float4 xr = *(const float4*)(x + ((size_t)b * 256 + o) * NPIX + qn);
    float xv[4] = {xr.x, xr.y, xr.z, xr.w};
#pragma unroll
    for (int r = 0; r < 4; ++r) {
      int row = tt * 16 + lq * 4 + r;
      float y = acc[0][ot][r] * Ls[0][row] + acc[1][ot][r] * Ls[1][row] +
                acc[2][ot][r] * Ls[2][row] + acc[3][ot][r] * Ls[3][row];
      float v = fmaxf(y * inv + off + xv[r], 0.f);
      u16 vb = f2b(v);
      zt[((size_t)b * NPIX + qn + r) * 256 + o] = vb;
      zl[row * ZLS + o] = vb;
    }
  }
  __syncthreads();
  // ---- phase 2: ff1. Wave (tt2,oc2): 16 rows x 16 out-ch, K=256 from LDS.
  const int oc2 = wave & 3, tt2 = wave >> 2;
  f32x4 a1 = {0.f, 0.f, 0.f, 0.f};
  const u16* Bw = f1b + (size_t)(oc2 * 16 + lr) * 256;
#pragma unroll
  for (int s = 0; s < 8; ++s) {
    bf16x8 a0 = *(const bf16x8*)(&zl[(tt2 * 16 + lr) * ZLS + s * 32 + lq * 8]);
    bf16x8 bw = *(const bf16x8*)(Bw + s * 32 + lq * 8);
    a1 = mfma(a0, bw, a1);
  }
  const int o1 = oc2 * 16 + lr;
  float inv1 = s1[o1] * rsqrtf(v1[o1] + 1e-5f);
  float off1 = b1[o1] - m1[o1] * inv1;
  const int pr = nb + tt2 * 16 + lq * 4;
#pragma unroll
  for (int r = 0; r < 4; ++r) {
    float v = fmaxf(a1[r] * inv1 + off1, 0.f);
    o1t[((size_t)b * NPIX + pr + r) * 64 + o1] = f2b(v);
  }
}

// ---------------------------------------------------------------------------
// ff2: R2 2-tile im2col MFMA. Grid (25,2,BB).
// ---------------------------------------------------------------------------
__global__ __launch_bounds__(256) void ff2_kernel(
    const u16* __restrict__ o1t, const u16* __restrict__ f2p,
    const float* __restrict__ sc, const float* __restrict__ bi,
    const float* __restrict__ mu, const float* __restrict__ var,
    u16* __restrict__ o2t) {
  const int b = blockIdx.z, oc = blockIdx.y, nb = blockIdx.x * 128;
  const int wv = threadIdx.x >> 6, lane = threadIdx.x & 63;
  const int lr = lane & 15, lq = lane >> 4;
  const int n0 = nb + wv * 32 + lr, n1 = n0 + 16;
  const int h0 = n0 / 56, w0 = n0 % 56;
  const int h1 = n1 / 56, w1 = n1 % 56;
  f32x4 acc[4] = {};
#pragma unroll
  for (int t = 0; t < 9; ++t) {
    const int dh = t / 3 - 1, dw = t % 3 - 1;
    const bool v0 = (h0 + dh) >= 0 && (h0 + dh) < 56 && (w0 + dw) >= 0 && (w0 + dw) < 56;
    const bool v1 = (h1 + dh) >= 0 && (h1 + dh) < 56 && (w1 + dw) >= 0 && (w1 + dw) < 56;
    const u16* A0 = o1t + ((size_t)b * NPIX + n0 + dh * 56 + dw) * 64;
    const u16* A1 = o1t + ((size_t)b * NPIX + n1 + dh * 56 + dw) * 64;
    const u16* Br = f2p + (size_t)t * 4096 + (size_t)(oc * 32 + lr) * 64;
#pragma unroll
    for (int k2 = 0; k2 < 2; ++k2) {
      bf16x8 bf0 = *(const bf16x8*)(Br + k2 * 32 + lq * 8);
      bf16x8 bf1 = *(const bf16x8*)(Br + (size_t)16 * 64 + k2 * 32 + lq * 8);
      bf16x8 a0 = {}, a1 = {};
      if (v0) a0 = *(const bf16x8*)(A0 + k2 * 32 + lq * 8);
      if (v1) a1 = *(const bf16x8*)(A1 + k2 * 32 + lq * 8);
      acc[0] = mfma(a0, bf0, acc[0]);
      acc[1] = mfma(a0, bf1, acc[1]);
      acc[2] = mfma(a1, bf0, acc[2]);
      acc[3] = mfma(a1, bf1, acc[3]);
    }
  }
  const int nrow0 = nb + wv * 32;
#pragma unroll
  for (int t = 0; t < 2; ++t) {
    const int qn = nrow0 + t * 16 + lq * 4;
    if (qn >= NPIX) continue;
#pragma unroll
    for (int ot = 0; ot < 2; ++ot) {
      const f32x4 a = acc[t * 2 + ot];
      const int o = oc * 32 + ot * 16 + lr;
      float inv = sc[o] * rsqrtf(var[o] + 1e-5f);
      float off = bi[o] - mu[o] * inv;
#pragma unroll
      for (int r = 0; r < 4; ++r) {
        float v = fmaxf(a[r] * inv + off, 0.f);
        o2t[((size_t)b * NPIX + qn + r) * 64 + o] = f2b(v);
      }
    }
  }
}

// ---------------------------------------------------------------------------
// ff3: R2 2-tile. Grid (25,4,BB).
// ---------------------------------------------------------------------------
__global__ __launch_bounds__(256) void ff3_kernel(
    const u16* __restrict__ o2t, const u16* __restrict__ f3b,
    const float* __restrict__ sc, const float* __restrict__ bi,
    const float* __restrict__ mu, const float* __restrict__ var,
    const u16* __restrict__ zt, float* __restrict__ out) {
  const int b = blockIdx.z, oc = blockIdx.y, nb = blockIdx.x * 128;
  const int wv = threadIdx.x >> 6, lane = threadIdx.x & 63;
  const int lr = lane & 15, lq = lane >> 4;
  const int nrow0 = nb + wv * 32, nrow1 = nrow0 + 16;
  const int r0 = nrow0 + lr < NPIX ? nrow0 + lr : NPIX - 1;
  const int r1 = nrow1 + lr < NPIX ? nrow1 + lr : NPIX - 1;
  f32x4 acc[8] = {};
  mf_gemm2<2, 4>(o2t + ((size_t)b * NPIX + r0) * 64,
                 o2t + ((size_t)b * NPIX + r1) * 64,
                 f3b + (size_t)(oc * 64 + lr) * 64, 64, lq, acc);
#pragma unroll
  for (int t = 0; t < 2; ++t) {
    const int qn = (t ? nrow1 : nrow0) + lq * 4;
    if (qn >= NPIX) continue;
#pragma unroll
    for (int ot = 0; ot < 4; ++ot) {
      const f32x4 a = acc[t * 4 + ot];
      const int o = oc * 64 + ot * 16 + lr;
      float inv = sc[o] * rsqrtf(var[o] + 1e-5f);
      float off = bi[o] - mu[o] * inv;
      float4 s;
      float* sv = (float*)&s;
#pragma unroll
      for (int r = 0; r < 4; ++r) {
        float zres = b2f(zt[((size_t)b * NPIX + qn + r) * 256 + o]);
        sv[r] = fmaxf(a[r] * inv + off + zres, 0.f);
      }
      *(float4*)(out + ((size_t)b * 256 + o) * NPIX + qn) = s;
    }
  }
}

// ---------------------------------------------------------------------------
extern "C" void kernel_launch(void* const* d_in, const int* in_sizes, int n_in,
                              void* d_out, int out_size, void* d_ws, size_t ws_size,
                              hipStream_t stream) {
  const float* x    = (const float*)d_in[0];
  const float* gw   = (const float*)d_in[1];
  const float* gb   = (const float*)d_in[2];
  const float* tw   = (const float*)d_in[3];
  const float* tb   = (const float*)d_in[4];
  const float* pw   = (const float*)d_in[5];
  const float* pb   = (const float*)d_in[6];
  const float* Ww   = (const float*)d_in[7];
  const float* Wb   = (const float*)d_in[8];
  const float* bnWs = (const float*)d_in[9];
  const float* bnWb = (const float*)d_in[10];
  const float* bnWm = (const float*)d_in[11];
  const float* bnWv = (const float*)d_in[12];
  const float* f1w  = (const float*)d_in[13];
  const float* b1s  = (const float*)d_in[14];
  const float* b1b  = (const float*)d_in[15];
  const float* b1m  = (const float*)d_in[16];
  const float* b1v  = (const float*)d_in[17];
  const float* f2w  = (const float*)d_in[18];
  const float* b2s  = (const float*)d_in[19];
  const float* b2b  = (const float*)d_in[20];
  const float* b2m  = (const float*)d_in[21];
  const float* b2v  = (const float*)d_in[22];
  const float* f3w  = (const float*)d_in[23];
  const float* b3s  = (const float*)d_in[24];
  const float* b3b  = (const float*)d_in[25];
  const float* b3m  = (const float*)d_in[26];
  const float* b3v  = (const float*)d_in[27];
  float* out = (float*)d_out;

  u16* p = (u16*)d_ws;
  u16* xt  = p; p += (size_t)BB * NPIX * 256;
  u16* gwb = p; p += 128 * 256;
  u16* twb = p; p += 128 * 256;
  u16* pwb = p; p += 128 * 256;
  u16* Wwb = p; p += 256 * 128;
  u16* f1b = p; p += 64 * 256;
  u16* f3b = p; p += 256 * 64;
  u16* f2p = p; p += 9 * 64 * 64;
  u16* Tq  = p; p += (size_t)16 * NPIX * 32;
  u16* Pk  = p; p += (size_t)16 * NPIX * 32;
  u16* gx  = p; p += (size_t)BB * 128 * NPIX;
  u16* OPb = p; p += (size_t)7 * 16 * NPIX * 32;   // bump kept at 7 (upper bound)
  float* LP = (float*)p; p += (size_t)7 * 16 * NPIX * 2;
  u16* zt  = p; p += (size_t)BB * NPIX * 256;
  u16* o1t = p; p += (size_t)BB * NPIX * 64;
  u16* o2t = p; p += (size_t)BB * NPIX * 64;

  prep_all<<<dim3(980), 256, 0, stream>>>(x, gw, tw, pw, Ww, f1w, f2w, f3w,
                                          xt, gwb, twb, pwb, Wwb, f1b, f3b, f2p);
  proj_kernel<<<dim3(25, 6, BB), 256, 0, stream>>>(xt, gwb, twb, pwb, gb, tb, pb,
                                                   gx, Tq, Pk);
  attn_kernel<<<dim3(NSPLIT * 400), 256, 0, stream>>>(Tq, Pk, gx, OPb, LP);
  wz_kernel<<<dim3(98, BB), 512, 0, stream>>>(OPb, LP, Wwb, Wb,
                                              bnWs, bnWb, bnWm, bnWv, x,
                                              f1b, b1s, b1b, b1m, b1v,
                                              zt, o1t);
  ff2_kernel<<<dim3(25, 2, BB), 256, 0, stream>>>(o1t, f2p, b2s, b2b, b2m, b2v, o2t);
  ff3_kernel<<<dim3(25, 4, BB), 256, 0, stream>>>(o2t, f3b, b3s, b3b, b3m, b3v, zt, out);
}